// Round 5
// baseline (1757.730 us; speedup 1.0000x reference)
//
#include <hip/hip_runtime.h>
#include <stdint.h>
#include <math.h>

#pragma clang fp contract(off)

#define NH 32
#define NKVH 8
#define SEQ 2048
#define HD 128
#define SCALING_F 0.08838834764831845f
#define OUT0_N (SEQ*NH*HD)   /* 8388608 */

typedef __attribute__((ext_vector_type(8))) short bf16x8;      // 8 bf16 = 4 VGPRs
typedef __attribute__((ext_vector_type(8))) _Float16 f16x8;    // 8 f16  = 4 VGPRs
typedef __attribute__((ext_vector_type(8))) unsigned short u16x8;
typedef __attribute__((ext_vector_type(4))) float f32x4;

// ---------------- threefry2x32 (JAX-compatible) ----------------
__host__ __device__ __forceinline__ void tf2x32(uint32_t k0, uint32_t k1,
    uint32_t x0, uint32_t x1, uint32_t* o0, uint32_t* o1) {
  uint32_t k2 = k0 ^ k1 ^ 0x1BD11BDAu;
  x0 += k0; x1 += k1;
#define TFR(r) { x0 += x1; x1 = (x1 << (r)) | (x1 >> (32 - (r))); x1 ^= x0; }
  TFR(13) TFR(15) TFR(26) TFR(6)
  x0 += k1; x1 += k2 + 1u;
  TFR(17) TFR(29) TFR(16) TFR(24)
  x0 += k2; x1 += k0 + 2u;
  TFR(13) TFR(15) TFR(26) TFR(6)
  x0 += k0; x1 += k1 + 3u;
  TFR(17) TFR(29) TFR(16) TFR(24)
  x0 += k1; x1 += k2 + 4u;
  TFR(13) TFR(15) TFR(26) TFR(6)
  x0 += k2; x1 += k0 + 5u;
#undef TFR
  *o0 = x0; *o1 = x1;
}

__device__ __forceinline__ float tf_uniform(uint32_t k0, uint32_t k1, uint32_t idx) {
  uint32_t a, b;
  tf2x32(k0, k1, 0u, idx, &a, &b);
  uint32_t bits = a ^ b;
  return __uint_as_float((bits >> 9) | 0x3f800000u) - 1.0f;
}

// ---------------- monotone float<->uint for atomic min/max ----------------
__device__ __forceinline__ unsigned fmono(float x) {
  unsigned u = __float_as_uint(x);
  return (u >> 31) ? ~u : (u | 0x80000000u);
}
__device__ __forceinline__ float funmono(unsigned m) {
  return __uint_as_float((m >> 31) ? (m ^ 0x80000000u) : ~m);
}

__device__ __forceinline__ void push_minmax(unsigned* slots, unsigned cm, unsigned cM) {
  volatile unsigned* vs = (volatile unsigned*)slots;
  if (cm < vs[0]) atomicMin(&slots[0], cm);
  if (cM > vs[1]) atomicMax(&slots[1], cM);
}

// bf16 truncation — exact for integer values <= 256 (our only use)
__device__ __forceinline__ unsigned short f2bf(float x) {
  return (unsigned short)(__float_as_uint(x) >> 16);
}

// fp16 hi/lo split: x ~= hi + lo with residual <= 2^-23 |x|
__device__ __forceinline__ void f16split(float x, unsigned short* h, unsigned short* l) {
  _Float16 hf = (_Float16)x;
  float r = x - (float)hf;         // exact (Sterbenz)
  _Float16 lf = (_Float16)r;
  *h = __builtin_bit_cast(unsigned short, hf);
  *l = __builtin_bit_cast(unsigned short, lf);
}

__device__ __forceinline__ float fq_st_i(float x, float lo, float hi, float scale,
                                         float scinv, float u) {
  float c = fminf(fmaxf(x, lo), hi);
  float t = (c - lo) * scinv;
  return floorf(t + u) * scale + lo;
}

// ---------------- swizzled LDS panel helpers ----------------
// 128-wide panel: [128 rows][128 2B], row stride 256B.
#define SWZ_OFF(row, c16) ((((row) * 256) + ((c16) * 16)) ^ (((row) & 7) << 4))
// 64-wide panel: [128 rows][64 2B], row stride 128B (8x16B slots/row).
#define SWZ64_OFF(row, c16) ((((row) * 128) + ((c16) * 16)) ^ (((row) & 7) << 4))

__device__ __forceinline__ void stage_panel(const unsigned short* __restrict__ g,
                                            int rowstride, unsigned short* s, int tid) {
#pragma unroll
  for (int it = 0; it < 8; ++it) {
    const int i = it * 256 + tid;
    const int row = i >> 4, c16 = i & 15;
    const u16x8 val = *(const u16x8*)&g[(size_t)row * rowstride + c16 * 8];
    *(u16x8*)((char*)s + SWZ_OFF(row, c16)) = val;
  }
}

__device__ __forceinline__ void stage_panel64(const unsigned short* __restrict__ g,
                                              int rowstride, unsigned short* s, int tid) {
#pragma unroll
  for (int it = 0; it < 4; ++it) {
    const int i = it * 256 + tid;
    const int row = i >> 3, c16 = i & 7;
    const u16x8 val = *(const u16x8*)&g[(size_t)row * rowstride + c16 * 8];
    *(u16x8*)((char*)s + SWZ64_OFF(row, c16)) = val;
  }
}

__device__ __forceinline__ f16x8 frag_h(const unsigned short* s, int row, int c16) {
  return *(const f16x8*)((const char*)s + SWZ_OFF(row, c16));
}
__device__ __forceinline__ bf16x8 frag_b(const unsigned short* s, int row, int c16) {
  return *(const bf16x8*)((const char*)s + SWZ_OFF(row, c16));
}
__device__ __forceinline__ f16x8 frag_h64(const unsigned short* s, int row, int c16) {
  return *(const f16x8*)((const char*)s + SWZ64_OFF(row, c16));
}
__device__ __forceinline__ bf16x8 frag_b64(const unsigned short* s, int row, int c16) {
  return *(const bf16x8*)((const char*)s + SWZ64_OFF(row, c16));
}

// ---------------- tiny kernels ----------------
__global__ void init_ws(unsigned* su) {
  int t = threadIdx.x;
  if (t < 12) su[t] = (t & 1) ? 0u : 0xFFFFFFFFu;
}

// cw stat block stride 8: [lo, hi, scale, lut_thr, inv_scale, _, _, _]
__device__ __forceinline__ void finalize_one(const unsigned* slots,
                                             const float* oldmm, float* outc) {
  float clo = funmono(slots[0]), chi = funmono(slots[1]);
  float o0 = oldmm[0], o1 = oldmm[1];
  bool fin = isfinite(o0) && isfinite(o1);
  float lo = fin ? (0.9f * o0 + 0.1f * clo) : clo;
  float hi = fin ? (0.9f * o1 + 0.1f * chi) : chi;
  float sc = (hi - lo) / 255.0f;
  outc[0] = lo;
  outc[1] = hi;
  outc[2] = sc;
  outc[3] = 0.02004f * fmaxf(fabsf(lo), fabsf(hi));
  outc[4] = 1.0f / sc;
}

__global__ void finalize_kernel(const unsigned* __restrict__ slots,
                                const float* __restrict__ oldmm,
                                float* __restrict__ outc) {
  if (threadIdx.x == 0) finalize_one(slots, oldmm, outc);
}

__global__ void finalize3_kernel(const unsigned* __restrict__ su,
                                 const float* __restrict__ q_old,
                                 const float* __restrict__ k_old,
                                 const float* __restrict__ v_old,
                                 float* __restrict__ cw) {
  int t = threadIdx.x;
  if (t == 0) finalize_one(su + 0, q_old, cw + 0);
  else if (t == 1) finalize_one(su + 2, k_old, cw + 8);
  else if (t == 2) finalize_one(su + 4, v_old, cw + 16);
}

// one launch for q/k/v input min/max: blocks [0,1024)=q, [1024,1536)=k, [1536,2048)=v
__global__ __launch_bounds__(256) void minmax3_kernel(const float4* __restrict__ q,
    const float4* __restrict__ k, const float4* __restrict__ v,
    unsigned* __restrict__ su) {
  const int b = blockIdx.x;
  const float4* x;
  int n4, b0, nb;
  unsigned* slots;
  if (b < 1024) { x = q; n4 = (NH * SEQ * HD) / 4; b0 = 0; nb = 1024; slots = su + 0; }
  else if (b < 1536) { x = k; n4 = (NKVH * SEQ * HD) / 4; b0 = 1024; nb = 512; slots = su + 2; }
  else { x = v; n4 = (NKVH * SEQ * HD) / 4; b0 = 1536; nb = 512; slots = su + 4; }
  float lmin = INFINITY, lmax = -INFINITY;
  for (int i = (b - b0) * 256 + threadIdx.x; i < n4; i += nb * 256) {
    float4 a = x[i];
    lmin = fminf(lmin, fminf(fminf(a.x, a.y), fminf(a.z, a.w)));
    lmax = fmaxf(lmax, fmaxf(fmaxf(a.x, a.y), fmaxf(a.z, a.w)));
  }
  __shared__ unsigned bmin, bmax;
  if (threadIdx.x == 0) { bmin = 0xFFFFFFFFu; bmax = 0u; }
  __syncthreads();
  atomicMin(&bmin, fmono(lmin));
  atomicMax(&bmax, fmono(lmax));
  __syncthreads();
  if (threadIdx.x == 0) push_minmax(slots, bmin, bmax);
}

// ---------------- merged quantization + split prepass ----------------
// blocks [0,8192): Q (2,097,152 float4s); [8192,10240): K (16384 rows, 8/blk);
// [10240,10496): V (8 kvh x 32 dg)
#define PREP_QB 8192
#define PREP_KB 2048
#define PREP_VB 256
__global__ __launch_bounds__(256) void prep_kernel(const float* __restrict__ q,
    const float* __restrict__ k, const float* __restrict__ v,
    unsigned short* __restrict__ qnb, unsigned short* __restrict__ qh,
    unsigned short* __restrict__ ql,
    unsigned short* __restrict__ kzb, unsigned short* __restrict__ kmb,
    unsigned short* __restrict__ kh, unsigned short* __restrict__ kl,
    float* __restrict__ Zk, float* __restrict__ Mk,
    unsigned short* __restrict__ vzT, unsigned short* __restrict__ vmT,
    unsigned short* __restrict__ vhT, unsigned short* __restrict__ vlT,
    const float* __restrict__ cw) {
  const int b = blockIdx.x, tid = threadIdx.x;
  if (b < PREP_QB) {
    const float lo = cw[0], hi = cw[1], sc = cw[2];
    int idx = b * 256 + tid;
    float4 x = ((const float4*)q)[idx];
    float xa[4] = {x.x, x.y, x.z, x.w};
    ushort4 o, oh, ol;
    unsigned short* op = (unsigned short*)&o;
    unsigned short* ohp = (unsigned short*)&oh;
    unsigned short* olp = (unsigned short*)&ol;
#pragma unroll
    for (int j = 0; j < 4; ++j) {
      float n = rintf((fminf(fmaxf(xa[j], lo), hi) - lo) / sc);
      op[j] = f2bf(n);
      f16split(xa[j], &ohp[j], &olp[j]);
    }
    ((ushort4*)qnb)[idx] = o;
    ((ushort4*)qh)[idx] = oh;
    ((ushort4*)ql)[idx] = ol;
  } else if (b < PREP_QB + PREP_KB) {
    const float lo = cw[8], hi = cw[9], sc = cw[10], thr = cw[11];
    const int row = (b - PREP_QB) * 8 + (tid >> 5);
    const int c4 = (tid & 31) * 4;
    float4 x = *(const float4*)&k[(size_t)row * HD + c4];
    float xa[4] = {x.x, x.y, x.z, x.w};
    ushort4 zo, mo, ho, lo_;
    unsigned short* zp = (unsigned short*)&zo;
    unsigned short* mp = (unsigned short*)&mo;
    unsigned short* hp = (unsigned short*)&ho;
    unsigned short* lp = (unsigned short*)&lo_;
    float zs = 0.f, ms = 0.f;
#pragma unroll
    for (int j = 0; j < 4; ++j) {
      float m = rintf((fminf(fmaxf(xa[j], lo), hi) - lo) / sc);
      float kq = m * sc + lo;
      float z = (fabsf(kq) < thr) ? 0.f : 1.f;
      float mq = z * m;
      zs += z; ms += mq;
      zp[j] = f2bf(z); mp[j] = f2bf(mq);
      f16split(xa[j], &hp[j], &lp[j]);
    }
    *(ushort4*)&kzb[(size_t)row * HD + c4] = zo;
    *(ushort4*)&kmb[(size_t)row * HD + c4] = mo;
    *(ushort4*)&kh[(size_t)row * HD + c4] = ho;
    *(ushort4*)&kl[(size_t)row * HD + c4] = lo_;
#pragma unroll
    for (int off = 16; off > 0; off >>= 1) {
      zs += __shfl_xor(zs, off);
      ms += __shfl_xor(ms, off);
    }
    if ((tid & 31) == 0) { Zk[row] = zs; Mk[row] = ms; }
  } else {
    const float lo = cw[16], hi = cw[17], sc = cw[18], thr = cw[19];
    const int b2 = b - (PREP_QB + PREP_KB);
    const int kvh = b2 >> 5, dg = b2 & 31;
    for (int ch = 0; ch < 8; ++ch) {
      int kp = ch * 256 + tid;
      float4 x = *(const float4*)&v[((size_t)(kvh * SEQ + kp)) * HD + dg * 4];
      float xa[4] = {x.x, x.y, x.z, x.w};
#pragma unroll
      for (int j = 0; j < 4; ++j) {
        float m = rintf((fminf(fmaxf(xa[j], lo), hi) - lo) / sc);
        float vq = m * sc + lo;
        float z = (fabsf(vq) < thr) ? 0.f : 1.f;
        float mq = z * m;
        size_t o = ((size_t)(kvh * HD + dg * 4 + j)) * SEQ + kp;
        vzT[o] = f2bf(z);
        vmT[o] = f2bf(mq);
        unsigned short hb, lb;
        f16split(xa[j], &hb, &lb);
        vhT[o] = hb;
        vlT[o] = lb;
      }
    }
  }
}

// ---------------- QK raw min/max via 3-term fp16-split MFMA, LDS-staged B ----------------
__global__ __launch_bounds__(256, 2) void qk_raw_mfma(
    const unsigned short* __restrict__ qh, const unsigned short* __restrict__ ql,
    const unsigned short* __restrict__ kh, const unsigned short* __restrict__ kl,
    unsigned* __restrict__ slots) {
  __shared__ __align__(16) unsigned short s_h[128 * 128];
  __shared__ __align__(16) unsigned short s_l[128 * 128];
  const int kbi = blockIdx.x, qbi = blockIdx.y, h = blockIdx.z;
  const int kvh = h >> 2;
  const int tid = threadIdx.x;
  const int wid = tid >> 6, lane = tid & 63;
  const int fr = lane & 15, fg = lane >> 4;
  const int qrow0 = qbi * 128 + wid * 32;
  const int kcol0 = kbi * 128;
  const unsigned short* qhg = qh + (size_t)h * SEQ * HD;
  const unsigned short* qlg = ql + (size_t)h * SEQ * HD;

  stage_panel(kh + ((size_t)kvh * SEQ + kcol0) * HD, HD, s_h, tid);
  stage_panel(kl + ((size_t)kvh * SEQ + kcol0) * HD, HD, s_l, tid);
  __syncthreads();

  f32x4 acc[2][8];
  const f32x4 z4 = {0.f, 0.f, 0.f, 0.f};
#pragma unroll
  for (int rg = 0; rg < 2; ++rg)
#pragma unroll
    for (int cg = 0; cg < 8; ++cg) acc[rg][cg] = z4;

#pragma unroll
  for (int ks = 0; ks < 4; ++ks) {
    const int d0 = ks * 32 + fg * 8;
    const int c16 = ks * 4 + fg;
    const f16x8 a0h = *(const f16x8*)&qhg[(size_t)(qrow0 + fr) * HD + d0];
    const f16x8 a0l = *(const f16x8*)&qlg[(size_t)(qrow0 + fr) * HD + d0];
    const f16x8 a1h = *(const f16x8*)&qhg[(size_t)(qrow0 + 16 + fr) * HD + d0];
    const f16x8 a1l = *(const f16x8*)&qlg[(size_t)(qrow0 + 16 + fr) * HD + d0];
#pragma unroll
    for (int cg = 0; cg < 8; ++cg) {
      const f16x8 bh = frag_h(s_h, cg * 16 + fr, c16);
      const f16x8 bl = frag_h(s_l, cg * 16 + fr, c16);
      acc[0][cg] = __builtin_amdgcn_mfma_f32_16x16x32_f16(a0h, bh, acc[0][cg], 0, 0, 0);
      acc[0][cg] = __builtin_amdgcn_mfma_f32_16x16x32_f16(a0h, bl, acc[0][cg], 0, 0, 0);
      acc[0][cg] = __builtin_amdgcn_mfma_f32_16x16x32_f16(a0l, bh, acc[0][cg], 0, 0, 0);
      acc[1][cg] = __builtin_amdgcn_mfma_f32_16x16x32_f16(a1h, bh, acc[1][cg], 0, 0, 0);
      acc[1][cg] = __builtin_amdgcn_mfma_f32_16x16x32_f16(a1h, bl, acc[1][cg], 0, 0, 0);
      acc[1][cg] = __builtin_amdgcn_mfma_f32_16x16x32_f16(a1l, bh, acc[1][cg], 0, 0, 0);
    }
  }
  float lmin = INFINITY, lmax = -INFINITY;
#pragma unroll
  for (int rg = 0; rg < 2; ++rg)
#pragma unroll
    for (int cg = 0; cg < 8; ++cg)
#pragma unroll
      for (int r = 0; r < 4; ++r) {
        const float rv = acc[rg][cg][r] * SCALING_F;
        lmin = fminf(lmin, rv);
        lmax = fmaxf(lmax, rv);
      }
  __shared__ unsigned bmin, bmax;
  if (tid == 0) { bmin = 0xFFFFFFFFu; bmax = 0u; }
  __syncthreads();
  atomicMin(&bmin, fmono(lmin));
  atomicMax(&bmax, fmono(lmax));
  __syncthreads();
  if (tid == 0) push_minmax(slots, bmin, bmax);
}

// ---------------- QK quant (bf16 MFMA, exact integer grid), LDS-staged B ----------------
__global__ __launch_bounds__(256, 2) void qk_quant_kernel(
    const unsigned short* __restrict__ qnb, const unsigned short* __restrict__ kzb,
    const unsigned short* __restrict__ kmb, const float* __restrict__ Zk,
    const float* __restrict__ Mk, float* __restrict__ qdot,
    const float* __restrict__ cw) {
  const int kbi = blockIdx.x, qbi = blockIdx.y, h = blockIdx.z;
  if (kbi > qbi) return;            // raw-only region above the diagonal
  __shared__ __align__(16) unsigned short s_z[128 * 128];
  __shared__ __align__(16) unsigned short s_m[128 * 128];
  const int kvh = h >> 2;
  const float qlo = cw[0], qsc = cw[2];
  const float klo = cw[8], ksc = cw[10];
  const int tid = threadIdx.x;
  const int wid = tid >> 6, lane = tid & 63;
  const int fr = lane & 15, fg = lane >> 4;
  const int qrow0 = qbi * 128 + wid * 32;
  const int kcol0 = kbi * 128;
  const unsigned short* qg = qnb + (size_t)h * SEQ * HD;

  stage_panel(kzb + ((size_t)kvh * SEQ + kcol0) * HD, HD, s_z, tid);
  stage_panel(kmb + ((size_t)kvh * SEQ + kcol0) * HD, HD, s_m, tid);
  __syncthreads();

  f32x4 P[2][8], R[2][8];
  const f32x4 z4 = {0.f, 0.f, 0.f, 0.f};
#pragma unroll
  for (int rg = 0; rg < 2; ++rg)
#pragma unroll
    for (int cg = 0; cg < 8; ++cg) { P[rg][cg] = z4; R[rg][cg] = z4; }

#pragma unroll
  for (int ks = 0; ks < 4; ++ks) {
    const int d0 = ks * 32 + fg * 8;
    const int c16 = ks * 4 + fg;
    const bf16x8 a0 = *(const bf16x8*)&qg[(size_t)(qrow0 + fr) * HD + d0];
    const bf16x8 a1 = *(const bf16x8*)&qg[(size_t)(qrow0 + 16 + fr) * HD + d0];
#pragma unroll
    for (int cg = 0; cg < 8; ++cg) {
      const bf16x8 bz = frag_b(s_z, cg * 16 + fr, c16);
      const bf16x8 bm = frag_b(s_m, cg * 16 + fr, c16);
      P[0][cg] = __builtin_amdgcn_mfma_f32_16x16x32_bf16(a0, bz, P[0][cg], 0, 0, 0);
      P[1][cg] = __builtin_amdgcn_mfma_f32_16x16x32_bf16(a1, bz, P[1][cg], 0, 0, 0);
      R[0][cg] = __builtin_amdgcn_mfma_f32_16x16x32_bf16(a0, bm, R[0][cg], 0, 0, 0);
      R[1][cg] = __builtin_amdgcn_mfma_f32_16x16x32_bf16(a1, bm, R[1][cg], 0, 0, 0);
    }
  }
#pragma unroll
  for (int cg = 0; cg < 8; ++cg) {
    const int col = kcol0 + cg * 16 + fr;
    const float Z = Zk[kvh * SEQ + col], M = Mk[kvh * SEQ + col];
    const float base = qlo * (klo * Z + ksc * M);
#pragma unroll
    for (int rg = 0; rg < 2; ++rg)
#pragma unroll
      for (int r = 0; r < 4; ++r) {
        const int row = qrow0 + rg * 16 + fg * 4 + r;
        qdot[((size_t)h * SEQ + row) * SEQ + col] =
            base + qsc * (klo * P[rg][cg][r] + ksc * R[rg][cg][r]);
      }
  }
}

// ---------------- softmax: causal skip + stoch-quant + softmax ----------------
__global__ __launch_bounds__(256) void softmax_kernel(
    float* __restrict__ attn, const float* __restrict__ cw,
    unsigned* __restrict__ slots, uint32_t uk0, uint32_t uk1) {
  const int row = blockIdx.x;          // h*SEQ + qi
  const int qi = row & (SEQ - 1);
  const int tid = threadIdx.x;
  const float lo = cw[24], hi = cw[25], sc = cw[26], sci = cw[28];
  float* prow = attn + (size_t)row * SEQ;
  const uint32_t jbase = (uint32_t)row << 11;

  float vals[8];
  float lmax = -INFINITY;
#pragma unroll
  for (int m = 0; m < 2; ++m) {
    int ki = m * 1024 + tid * 4;
    if (ki <= qi) {
      float4 x4 = *(const float4*)&prow[ki];
      float xa[4] = {x4.x, x4.y, x4.z, x4.w};
#pragma unroll
      for (int j = 0; j < 4; ++j) {
        if (ki + j <= qi) {
          float u = tf_uniform(uk0, uk1, jbase + (uint32_t)(ki + j));
          float lg = fq_st_i(xa[j], lo, hi, sc, sci, u) * SCALING_F;
          vals[m * 4 + j] = lg;
          lmax = fmaxf(lmax, lg);
        } else {
          vals[m * 4 + j] = -INFINITY;
        }
      }
    } else {
      vals[m * 4 + 0] = vals[m * 4 + 1] = vals[m * 4 + 2] = vals[m * 4 + 3] = -INFINITY;
    }
  }

  __shared__ float smax[4], ssum[4], smn[4], smx[4];
#pragma unroll
  for (int off = 32; off > 0; off >>= 1) lmax = fmaxf(lmax, __shfl_xor(lmax, off));
  if ((tid & 63) == 0) smax[tid >> 6] = lmax;
  __syncthreads();
  float rmax = fmaxf(fmaxf(smax[0], smax[1]), fmaxf(smax[2], smax[3]));

  float lsum = 0.f;
#pragma unroll
  for (int e = 0; e < 8; ++e) { vals[e] = __expf(vals[e] - rmax); lsum += vals[e]; }
#pragma unroll
  for (int off = 32; off > 0; off >>= 1) lsum += __shfl_xor(lsum, off);
  if ((tid & 63) == 0) ssum[tid >> 6] = lsum;
  __syncthreads();
  float rinv = 1.0f / (ssum[0] + ssum[1] + ssum[2] + ssum[3]);

  float lmin2 = INFINITY, lmax2 = -INFINITY;
#pragma unroll
  for (int m = 0; m < 2; ++m) {
    int ki = m * 1024 + tid * 4;
    float4 st;
    float* stp = (float*)&st;
#pragma unroll
    for (int j = 0; j < 4; ++j) {
      float w = vals[m * 4 + j] * rinv;
      stp[j] = w;
      lmin2 = fminf(lmin2, w);
      lmax2 = fmaxf(lmax2, w);
    }
    *(float4*)&prow[ki] = st;
  }
#pragma unroll
  for (int off = 32; off > 0; off >>= 1) {
    lmin2 = fminf(lmin2, __shfl_xor(lmin2, off));
    lmax2 = fmaxf(lmax2, __shfl_xor(lmax2, off));
  }
  if ((tid & 63) == 0) { smn[tid >> 6] = lmin2; smx[tid >> 6] = lmax2; }
  __syncthreads();
  if (tid == 0) {
    float mn = fminf(fminf(smn[0], smn[1]), fminf(smn[2], smn[3]));
    float mx = fmaxf(fmaxf(smx[0], smx[1]), fmaxf(smx[2], smx[3]));
    push_minmax(slots, fmono(mn), fmono(mx));
  }
}

// ---------------- packers ----------------
__device__ __forceinline__ void pack_split8(const float* __restrict__ p,
                                            f16x8* ah, f16x8* al) {
  float4 w0 = *(const float4*)p;
  float4 w1 = *(const float4*)(p + 4);
  float wa[8] = {w0.x, w0.y, w0.z, w0.w, w1.x, w1.y, w1.z, w1.w};
  f16x8 h, l;
#pragma unroll
  for (int j = 0; j < 8; ++j) {
    _Float16 hf = (_Float16)wa[j];
    h[j] = hf;
    l[j] = (_Float16)(wa[j] - (float)hf);
  }
  *ah = h; *al = l;
}

__device__ __forceinline__ bf16x8 pack_a8(const float* __restrict__ ar,
                                          float lo, float hi, float sc) {
  float4 w0 = *(const float4*)ar;
  float4 w1 = *(const float4*)(ar + 4);
  float wa[8] = {w0.x, w0.y, w0.z, w0.w, w1.x, w1.y, w1.z, w1.w};
  bf16x8 r;
#pragma unroll
  for (int j = 0; j < 8; ++j) {
    float n = rintf((fminf(fmaxf(wa[j], lo), hi) - lo) / sc);
    r[j] = (short)(__float_as_uint(n) >> 16);
  }
  return r;
}

// one attn read -> integer-grid bf16 + f16 hi/lo (shared loads)
__device__ __forceinline__ void pack_all(const float* __restrict__ p,
    float lo, float hi, float sc, bf16x8* an, f16x8* ah, f16x8* al) {
  float4 w0 = *(const float4*)p;
  float4 w1 = *(const float4*)(p + 4);
  float wa[8] = {w0.x, w0.y, w0.z, w0.w, w1.x, w1.y, w1.z, w1.w};
  bf16x8 n8; f16x8 h8, l8;
#pragma unroll
  for (int j = 0; j < 8; ++j) {
    float n = rintf((fminf(fmaxf(wa[j], lo), hi) - lo) / sc);
    n8[j] = (short)(__float_as_uint(n) >> 16);
    _Float16 hf = (_Float16)wa[j];
    h8[j] = hf;
    l8[j] = (_Float16)(wa[j] - (float)hf);
  }
  *an = n8; *ah = h8; *al = l8;
}

// ---------------- AV raw (3-term f16 MFMA) — fallback split path ----------------
__global__ __launch_bounds__(256, 2) void av_raw_mfma(
    const float* __restrict__ attn, const unsigned short* __restrict__ vhT,
    const unsigned short* __restrict__ vlT, unsigned* __restrict__ slots) {
  __shared__ __align__(16) unsigned short s_h[128 * 128];
  __shared__ __align__(16) unsigned short s_l[128 * 128];
  const int qbi = (int)gridDim.x - 1 - (int)blockIdx.x;
  const int h = blockIdx.y, kvh = h >> 2;
  const int tid = threadIdx.x;
  const int wid = tid >> 6, lane = tid & 63;
  const int fr = lane & 15, fg = lane >> 4;
  const int qrow0 = qbi * 128 + wid * 32;
  const float* ag = attn + (size_t)h * SEQ * SEQ;
  const unsigned short* bhg = vhT + (size_t)kvh * HD * SEQ;
  const unsigned short* blg = vlT + (size_t)kvh * HD * SEQ;
  const int nc = qbi + 1;
  f32x4 acc[2][8];
  const f32x4 z4 = {0.f, 0.f, 0.f, 0.f};
#pragma unroll
  for (int rg = 0; rg < 2; ++rg)
#pragma unroll
    for (int cg = 0; cg < 8; ++cg) acc[rg][cg] = z4;

  for (int c = 0; c < nc; ++c) {
    __syncthreads();
    stage_panel(bhg + c * 128, SEQ, s_h, tid);
    stage_panel(blg + c * 128, SEQ, s_l, tid);
    __syncthreads();
#pragma unroll
    for (int ks = 0; ks < 4; ++ks) {
      const int kp0 = c * 128 + ks * 32 + fg * 8;
      const int c16 = ks * 4 + fg;
      f16x8 a0h, a0l, a1h, a1l;
      pack_split8(ag + (size_t)(qrow0 + fr) * SEQ + kp0, &a0h, &a0l);
      pack_split8(ag + (size_t)(qrow0 + 16 + fr) * SEQ + kp0, &a1h, &a1l);
#pragma unroll
      for (int cg = 0; cg < 8; ++cg) {
        const f16x8 bh = frag_h(s_h, cg * 16 + fr, c16);
        const f16x8 bl = frag_h(s_l, cg * 16 + fr, c16);
        acc[0][cg] = __builtin_amdgcn_mfma_f32_16x16x32_f16(a0h, bh, acc[0][cg], 0, 0, 0);
        acc[0][cg] = __builtin_amdgcn_mfma_f32_16x16x32_f16(a0h, bl, acc[0][cg], 0, 0, 0);
        acc[0][cg] = __builtin_amdgcn_mfma_f32_16x16x32_f16(a0l, bh, acc[0][cg], 0, 0, 0);
        acc[1][cg] = __builtin_amdgcn_mfma_f32_16x16x32_f16(a1h, bh, acc[1][cg], 0, 0, 0);
        acc[1][cg] = __builtin_amdgcn_mfma_f32_16x16x32_f16(a1h, bl, acc[1][cg], 0, 0, 0);
        acc[1][cg] = __builtin_amdgcn_mfma_f32_16x16x32_f16(a1l, bh, acc[1][cg], 0, 0, 0);
      }
    }
  }
  float lmin = INFINITY, lmax = -INFINITY;
#pragma unroll
  for (int rg = 0; rg < 2; ++rg)
#pragma unroll
    for (int cg = 0; cg < 8; ++cg)
#pragma unroll
      for (int r = 0; r < 4; ++r) {
        lmin = fminf(lmin, acc[rg][cg][r]);
        lmax = fmaxf(lmax, acc[rg][cg][r]);
      }
  __shared__ unsigned bmin, bmax;
  if (tid == 0) { bmin = 0xFFFFFFFFu; bmax = 0u; }
  __syncthreads();
  atomicMin(&bmin, fmono(lmin));
  atomicMax(&bmax, fmono(lmax));
  __syncthreads();
  if (tid == 0) push_minmax(slots, bmin, bmax);
}

// ---------------- AV quant — fallback split path ----------------
__global__ __launch_bounds__(256, 2) void av_quant_kernel(
    const float* __restrict__ attn, const unsigned short* __restrict__ vzT,
    const unsigned short* __restrict__ vmT, float* __restrict__ out0,
    const float* __restrict__ cw) {
  __shared__ __align__(16) unsigned short s_z[128 * 128];
  __shared__ __align__(16) unsigned short s_m[128 * 128];
  const int qbi = (int)gridDim.x - 1 - (int)blockIdx.x;
  const int h = blockIdx.y, kvh = h >> 2;
  const float alo = cw[32], ahi = cw[33], asc = cw[34];
  const float vlo = cw[16], vsc = cw[18];
  const int tid = threadIdx.x;
  const int wid = tid >> 6, lane = tid & 63;
  const int fr = lane & 15, fg = lane >> 4;
  const int qrow0 = qbi * 128 + wid * 32;
  const float* ag = attn + (size_t)h * SEQ * SEQ;
  const unsigned short* zg = vzT + (size_t)kvh * HD * SEQ;
  const unsigned short* mg = vmT + (size_t)kvh * HD * SEQ;
  const int nc = qbi + 1;
  f32x4 P[2][8], R[2][8];
  const f32x4 z4 = {0.f, 0.f, 0.f, 0.f};
#pragma unroll
  for (int rg = 0; rg < 2; ++rg)
#pragma unroll
    for (int cg = 0; cg < 8; ++cg) { P[rg][cg] = z4; R[rg][cg] = z4; }

  for (int c = 0; c < nc; ++c) {
    __syncthreads();
    stage_panel(zg + c * 128, SEQ, s_z, tid);
    stage_panel(mg + c * 128, SEQ, s_m, tid);
    __syncthreads();
#pragma unroll
    for (int ks = 0; ks < 4; ++ks) {
      const int kp0 = c * 128 + ks * 32 + fg * 8;
      const int c16 = ks * 4 + fg;
      const bf16x8 a0 = pack_a8(ag + (size_t)(qrow0 + fr) * SEQ + kp0, alo, ahi, asc);
      const bf16x8 a1 = pack_a8(ag + (size_t)(qrow0 + 16 + fr) * SEQ + kp0, alo, ahi, asc);
#pragma unroll
      for (int cg = 0; cg < 8; ++cg) {
        const bf16x8 bz = frag_b(s_z, cg * 16 + fr, c16);
        const bf16x8 bm = frag_b(s_m, cg * 16 + fr, c16);
        P[0][cg] = __builtin_amdgcn_mfma_f32_16x16x32_bf16(a0, bz, P[0][cg], 0, 0, 0);
        P[1][cg] = __builtin_amdgcn_mfma_f32_16x16x32_bf16(a1, bz, P[1][cg], 0, 0, 0);
        R[0][cg] = __builtin_amdgcn_mfma_f32_16x16x32_bf16(a0, bm, R[0][cg], 0, 0, 0);
        R[1][cg] = __builtin_amdgcn_mfma_f32_16x16x32_bf16(a1, bm, R[1][cg], 0, 0, 0);
      }
    }
  }
#pragma unroll
  for (int cg = 0; cg < 8; ++cg) {
    const int dcol = cg * 16 + fr;
#pragma unroll
    for (int rg = 0; rg < 2; ++rg)
#pragma unroll
      for (int r = 0; r < 4; ++r) {
        const int row = qrow0 + rg * 16 + fg * 4 + r;
        out0[((size_t)row * NH + h) * HD + dcol] =
            asc * (vlo * P[rg][cg][r] + vsc * R[rg][cg][r]);
      }
  }
}

// ---------------- AV fused: raw minmax + quant output in one pass ----------------
// 64-row blocks (1 row-group/wave), 64-kp chunks, 4x16KB swizzled panels.
// vhT/vlT must NOT alias out0 (reads concurrent with out0 writes) -> ws-resident.
__global__ __launch_bounds__(256, 2) void av_fused_kernel(
    const float* __restrict__ attn,
    const unsigned short* __restrict__ vzT, const unsigned short* __restrict__ vmT,
    const unsigned short* __restrict__ vhT, const unsigned short* __restrict__ vlT,
    float* __restrict__ out0, const float* __restrict__ cw,
    unsigned* __restrict__ slots) {
  __shared__ __align__(16) unsigned short s_z[128 * 64];
  __shared__ __align__(16) unsigned short s_m[128 * 64];
  __shared__ __align__(16) unsigned short s_h[128 * 64];
  __shared__ __align__(16) unsigned short s_l[128 * 64];
  const int qbi2 = (int)gridDim.x - 1 - (int)blockIdx.x;  // largest first
  const int h = blockIdx.y, kvh = h >> 2;
  const float alo = cw[32], ahi = cw[33], asc = cw[34];
  const float vlo = cw[16], vsc = cw[18];
  const int tid = threadIdx.x;
  const int wid = tid >> 6, lane = tid & 63;
  const int fr = lane & 15, fg = lane >> 4;
  const int qrow0 = qbi2 * 64 + wid * 16;
  const float* ag = attn + (size_t)h * SEQ * SEQ;
  const unsigned short* zg = vzT + (size_t)kvh * HD * SEQ;
  const unsigned short* mg = vmT + (size_t)kvh * HD * SEQ;
  const unsigned short* hg = vhT + (size_t)kvh * HD * SEQ;
  const unsigned short* lg = vlT + (size_t)kvh * HD * SEQ;
  const int nc = qbi2 + 1;   // 64-kp chunks; attn cols beyond qb+63 are exactly 0
  f32x4 A[8], P[8], R[8];
  const f32x4 z4 = {0.f, 0.f, 0.f, 0.f};
#pragma unroll
  for (int cg = 0; cg < 8; ++cg) { A[cg] = z4; P[cg] = z4; R[cg] = z4; }

  for (int c = 0; c < nc; ++c) {
    __syncthreads();
    stage_panel64(zg + c * 64, SEQ, s_z, tid);
    stage_panel64(mg + c * 64, SEQ, s_m, tid);
    stage_panel64(hg + c * 64, SEQ, s_h, tid);
    stage_panel64(lg + c * 64, SEQ, s_l, tid);
    __syncthreads();
#pragma unroll
    for (int ks = 0; ks < 2; ++ks) {
      const int kp0 = c * 64 + ks * 32 + fg * 8;
      const int c16 = ks * 4 + fg;
      bf16x8 an; f16x8 ah, al;
      pack_all(ag + (size_t)(qrow0 + fr) * SEQ + kp0, alo, ahi, asc, &an, &ah, &al);
#pragma unroll
      for (int cg = 0; cg < 8; ++cg) {
        const int brow = cg * 16 + fr;
        const bf16x8 bz = frag_b64(s_z, brow, c16);
        const bf16x8 bm = frag_b64(s_m, brow, c16);
        const f16x8 bh = frag_h64(s_h, brow, c16);
        const f16x8 bl = frag_h64(s_l, brow, c16);
        P[cg] = __builtin_amdgcn_mfma_f32_16x16x32_bf16(an, bz, P[cg], 0, 0, 0);
        R[cg] = __builtin_amdgcn_mfma_f32_16x16x32_bf16(an, bm, R[cg], 0, 0, 0);
        A[cg] = __builtin_amdgcn_mfma_f32_16x16x32_f16(ah, bh, A[cg], 0, 0, 0);
        A[cg] = __builtin_amdgcn_mfma_f32_16x16x32_f16(ah, bl, A[cg], 0, 0, 0);
        A[cg] = __builtin_amdgcn_mfma_f32_16x16x32_f16(al, bh, A[cg], 0, 0, 0);
      }
    }
  }
  float lmin = INFINITY, lmax = -INFINITY;
#pragma unroll
  for (int cg = 0; cg < 8; ++cg)
#pragma unroll
    for (int r = 0; r < 4; ++r) {
      lmin = fminf(lmin, A[cg][r]);
      lmax = fmaxf(lmax, A[cg][r]);
    }
#pragma unroll
  for (int cg = 0; cg < 8; ++cg) {
    const int dcol = cg * 16 + fr;
#pragma unroll
    for (int r = 0; r < 4; ++r) {
      const int row = qrow0 + fg * 4 + r;
      out0[((size_t)row * NH + h) * HD + dcol] =
          asc * (vlo * P[cg][r] + vsc * R[cg][r]);
    }
  }
  __shared__ unsigned bmin, bmax;
  if (tid == 0) { bmin = 0xFFFFFFFFu; bmax = 0u; }
  __syncthreads();
  atomicMin(&bmin, fmono(lmin));
  atomicMax(&bmax, fmono(lmax));
  __syncthreads();
  if (tid == 0) push_minmax(slots, bmin, bmax);
}

// ---------------- final elementwise stochastic quantization of out0 ----------------
__global__ __launch_bounds__(256) void stoch_kernel(float* __restrict__ out0,
                                                    const float* __restrict__ cw,
                                                    uint32_t uk0, uint32_t uk1) {
  int idx = blockIdx.x * 256 + threadIdx.x;
  const float lo = cw[40], hi = cw[41], sc = cw[42], sci = cw[44];
  int qi = idx >> 12;                 // / (NH*HD)
  int rem = idx & 4095;
  int h = rem >> 7, d = rem & 127;
  uint32_t j = ((uint32_t)h * SEQ + (uint32_t)qi) * HD + (uint32_t)d;  // BHSD flat
  float x = out0[idx];
  float u = tf_uniform(uk0, uk1, j);
  out0[idx] = fq_st_i(x, lo, hi, sc, sci, u);
}

// ---------------- launcher ----------------
extern "C" void kernel_launch(void* const* d_in, const int* in_sizes, int n_in,
                              void* d_out, int out_size, void* d_ws, size_t ws_size,
                              hipStream_t stream) {
  (void)in_sizes; (void)n_in; (void)out_size;
  const float* q      = (const float*)d_in[0];
  const float* k      = (const float*)d_in[1];
  const float* v      = (const float*)d_in[2];
  const float* q_old  = (const float*)d_in[4];
  const float* k_old  = (const float*)d_in[5];
  const float* qk_old = (const float*)d_in[6];
  const float* a_old  = (const float*)d_in[7];
  const float* v_old  = (const float*)d_in[8];
  const float* av_old = (const float*)d_in[9];
  float* out0 = (float*)d_out;
  float* out1 = out0 + (size_t)OUT0_N;
  unsigned* su = (unsigned*)d_ws;
  float* cw = (float*)d_ws + 16;

  // d_ws scratch: vzT/vmT + Zk/Mk (+ vhT/vlT when room)
  unsigned short* vzT = (unsigned short*)((char*)d_ws + 1024);
  unsigned short* vmT = vzT + (size_t)NKVH * SEQ * HD;
  float* Zk = (float*)(vmT + (size_t)NKVH * SEQ * HD);
  float* Mk = Zk + NKVH * SEQ;
  unsigned short* vhT_ws = (unsigned short*)(Mk + NKVH * SEQ);
  unsigned short* vlT_ws = vhT_ws + (size_t)NKVH * SEQ * HD;
  const int use_fused = ws_size >= (size_t)18 * 1024 * 1024;

  // out0-region scratch (consumed before out0 is written):
  // qnb(16MB) kzb(4MB) kmb(4MB) [vhT(4MB) vlT(4MB) only in fallback]
  unsigned short* qnb = (unsigned short*)out0;
  unsigned short* kzb = qnb + (size_t)NH * SEQ * HD;
  unsigned short* kmb = kzb + (size_t)NKVH * SEQ * HD;
  unsigned short* vhT_o = kmb + (size_t)NKVH * SEQ * HD;
  unsigned short* vlT_o = vhT_o + (size_t)NKVH * SEQ * HD;
  unsigned short* vhT = use_fused ? vhT_ws : vhT_o;
  unsigned short* vlT = use_fused ? vlT_ws : vlT_o;

  // out1-region scratch (consumed by qk_raw_mfma before qk_quant writes out1)
  unsigned short* qh = (unsigned short*)out1;
  unsigned short* ql = qh + (size_t)NH * SEQ * HD;
  unsigned short* kh = ql + (size_t)NH * SEQ * HD;
  unsigned short* kl = kh + (size_t)NKVH * SEQ * HD;

  uint32_t kq0, kq1, ka0, ka1;
  tf2x32(0u, 0u, 0u, 0u, &kq0, &kq1);
  tf2x32(0u, 0u, 0u, 1u, &ka0, &ka1);

  init_ws<<<1, 32, 0, stream>>>(su);
  minmax3_kernel<<<2048, 256, 0, stream>>>((const float4*)q, (const float4*)k,
                                           (const float4*)v, su);
  finalize3_kernel<<<1, 32, 0, stream>>>(su, q_old, k_old, v_old, cw);
  prep_kernel<<<PREP_QB + PREP_KB + PREP_VB, 256, 0, stream>>>(
      q, k, v, qnb, qh, ql, kzb, kmb, kh, kl, Zk, Mk, vzT, vmT, vhT, vlT, cw);

  qk_raw_mfma<<<dim3(16, 16, NH), 256, 0, stream>>>(qh, ql, kh, kl, su + 6);
  finalize_kernel<<<1, 1, 0, stream>>>(su + 6, qk_old, cw + 24);
  qk_quant_kernel<<<dim3(16, 16, NH), 256, 0, stream>>>(qnb, kzb, kmb, Zk, Mk, out1, cw);

  softmax_kernel<<<NH * SEQ, 256, 0, stream>>>(out1, cw, su + 8, kq0, kq1);
  finalize_kernel<<<1, 1, 0, stream>>>(su + 8, a_old, cw + 32);

  if (use_fused) {
    av_fused_kernel<<<dim3(32, NH), 256, 0, stream>>>(out1, vzT, vmT, vhT, vlT,
                                                      out0, cw, su + 10);
    finalize_kernel<<<1, 1, 0, stream>>>(su + 10, av_old, cw + 40);
  } else {
    av_raw_mfma<<<dim3(16, NH), 256, 0, stream>>>(out1, vhT, vlT, su + 10);
    finalize_kernel<<<1, 1, 0, stream>>>(su + 10, av_old, cw + 40);
    av_quant_kernel<<<dim3(16, NH), 256, 0, stream>>>(out1, vzT, vmT, out0, cw);
  }

  stoch_kernel<<<OUT0_N / 256, 256, 0, stream>>>(out0, cw, ka0, ka1);
}

// Round 6
// 1562.954 us; speedup vs baseline: 1.1246x; 1.1246x over previous
//
#include <hip/hip_runtime.h>
#include <stdint.h>
#include <math.h>

#pragma clang fp contract(off)

#define NH 32
#define NKVH 8
#define SEQ 2048
#define HD 128
#define SCALING_F 0.08838834764831845f
#define OUT0_N (SEQ*NH*HD)   /* 8388608 */

typedef __attribute__((ext_vector_type(8))) short bf16x8;      // 8 bf16 = 4 VGPRs
typedef __attribute__((ext_vector_type(8))) _Float16 f16x8;    // 8 f16  = 4 VGPRs
typedef __attribute__((ext_vector_type(8))) unsigned short u16x8;
typedef __attribute__((ext_vector_type(4))) float f32x4;

// ---------------- threefry2x32 (JAX-compatible) ----------------
__host__ __device__ __forceinline__ void tf2x32(uint32_t k0, uint32_t k1,
    uint32_t x0, uint32_t x1, uint32_t* o0, uint32_t* o1) {
  uint32_t k2 = k0 ^ k1 ^ 0x1BD11BDAu;
  x0 += k0; x1 += k1;
#define TFR(r) { x0 += x1; x1 = (x1 << (r)) | (x1 >> (32 - (r))); x1 ^= x0; }
  TFR(13) TFR(15) TFR(26) TFR(6)
  x0 += k1; x1 += k2 + 1u;
  TFR(17) TFR(29) TFR(16) TFR(24)
  x0 += k2; x1 += k0 + 2u;
  TFR(13) TFR(15) TFR(26) TFR(6)
  x0 += k0; x1 += k1 + 3u;
  TFR(17) TFR(29) TFR(16) TFR(24)
  x0 += k1; x1 += k2 + 4u;
  TFR(13) TFR(15) TFR(26) TFR(6)
  x0 += k2; x1 += k0 + 5u;
#undef TFR
  *o0 = x0; *o1 = x1;
}

__device__ __forceinline__ float tf_uniform(uint32_t k0, uint32_t k1, uint32_t idx) {
  uint32_t a, b;
  tf2x32(k0, k1, 0u, idx, &a, &b);
  uint32_t bits = a ^ b;
  return __uint_as_float((bits >> 9) | 0x3f800000u) - 1.0f;
}

// ---------------- monotone float<->uint for atomic min/max ----------------
__device__ __forceinline__ unsigned fmono(float x) {
  unsigned u = __float_as_uint(x);
  return (u >> 31) ? ~u : (u | 0x80000000u);
}
__device__ __forceinline__ float funmono(unsigned m) {
  return __uint_as_float((m >> 31) ? (m ^ 0x80000000u) : ~m);
}

__device__ __forceinline__ void push_minmax(unsigned* slots, unsigned cm, unsigned cM) {
  volatile unsigned* vs = (volatile unsigned*)slots;
  if (cm < vs[0]) atomicMin(&slots[0], cm);
  if (cM > vs[1]) atomicMax(&slots[1], cM);
}

// bf16 truncation — exact for integer values <= 256 (our only use)
__device__ __forceinline__ unsigned short f2bf(float x) {
  return (unsigned short)(__float_as_uint(x) >> 16);
}

// fp16 hi/lo split: x ~= hi + lo with residual <= 2^-23 |x|
__device__ __forceinline__ void f16split(float x, unsigned short* h, unsigned short* l) {
  _Float16 hf = (_Float16)x;
  float r = x - (float)hf;         // exact (Sterbenz)
  _Float16 lf = (_Float16)r;
  *h = __builtin_bit_cast(unsigned short, hf);
  *l = __builtin_bit_cast(unsigned short, lf);
}

__device__ __forceinline__ float fq_st_i(float x, float lo, float hi, float scale,
                                         float scinv, float u) {
  float c = fminf(fmaxf(x, lo), hi);
  float t = (c - lo) * scinv;
  return floorf(t + u) * scale + lo;
}

// ---------------- swizzled LDS panel helpers ----------------
// 128-wide panel: [128 rows][128 2B], row stride 256B.
#define SWZ_OFF(row, c16) ((((row) * 256) + ((c16) * 16)) ^ (((row) & 7) << 4))

__device__ __forceinline__ void stage_panel(const unsigned short* __restrict__ g,
                                            int rowstride, unsigned short* s, int tid) {
#pragma unroll
  for (int it = 0; it < 8; ++it) {
    const int i = it * 256 + tid;
    const int row = i >> 4, c16 = i & 15;
    const u16x8 val = *(const u16x8*)&g[(size_t)row * rowstride + c16 * 8];
    *(u16x8*)((char*)s + SWZ_OFF(row, c16)) = val;
  }
}

__device__ __forceinline__ f16x8 frag_h(const unsigned short* s, int row, int c16) {
  return *(const f16x8*)((const char*)s + SWZ_OFF(row, c16));
}
__device__ __forceinline__ bf16x8 frag_b(const unsigned short* s, int row, int c16) {
  return *(const bf16x8*)((const char*)s + SWZ_OFF(row, c16));
}

// ---------------- tiny kernels ----------------
__global__ void init_ws(unsigned* su) {
  int t = threadIdx.x;
  if (t < 12) su[t] = (t & 1) ? 0u : 0xFFFFFFFFu;
}

// cw stat block stride 8: [lo, hi, scale, lut_thr, inv_scale, _, _, _]
__device__ __forceinline__ void finalize_one(const unsigned* slots,
                                             const float* oldmm, float* outc) {
  float clo = funmono(slots[0]), chi = funmono(slots[1]);
  float o0 = oldmm[0], o1 = oldmm[1];
  bool fin = isfinite(o0) && isfinite(o1);
  float lo = fin ? (0.9f * o0 + 0.1f * clo) : clo;
  float hi = fin ? (0.9f * o1 + 0.1f * chi) : chi;
  float sc = (hi - lo) / 255.0f;
  outc[0] = lo;
  outc[1] = hi;
  outc[2] = sc;
  outc[3] = 0.02004f * fmaxf(fabsf(lo), fabsf(hi));
  outc[4] = 1.0f / sc;
}

__global__ void finalize_kernel(const unsigned* __restrict__ slots,
                                const float* __restrict__ oldmm,
                                float* __restrict__ outc) {
  if (threadIdx.x == 0) finalize_one(slots, oldmm, outc);
}

__global__ void finalize3_kernel(const unsigned* __restrict__ su,
                                 const float* __restrict__ q_old,
                                 const float* __restrict__ k_old,
                                 const float* __restrict__ v_old,
                                 float* __restrict__ cw) {
  int t = threadIdx.x;
  if (t == 0) finalize_one(su + 0, q_old, cw + 0);
  else if (t == 1) finalize_one(su + 2, k_old, cw + 8);
  else if (t == 2) finalize_one(su + 4, v_old, cw + 16);
}

// one launch for q/k/v input min/max: blocks [0,1024)=q, [1024,1536)=k, [1536,2048)=v
__global__ __launch_bounds__(256) void minmax3_kernel(const float4* __restrict__ q,
    const float4* __restrict__ k, const float4* __restrict__ v,
    unsigned* __restrict__ su) {
  const int b = blockIdx.x;
  const float4* x;
  int n4, b0, nb;
  unsigned* slots;
  if (b < 1024) { x = q; n4 = (NH * SEQ * HD) / 4; b0 = 0; nb = 1024; slots = su + 0; }
  else if (b < 1536) { x = k; n4 = (NKVH * SEQ * HD) / 4; b0 = 1024; nb = 512; slots = su + 2; }
  else { x = v; n4 = (NKVH * SEQ * HD) / 4; b0 = 1536; nb = 512; slots = su + 4; }
  float lmin = INFINITY, lmax = -INFINITY;
  for (int i = (b - b0) * 256 + threadIdx.x; i < n4; i += nb * 256) {
    float4 a = x[i];
    lmin = fminf(lmin, fminf(fminf(a.x, a.y), fminf(a.z, a.w)));
    lmax = fmaxf(lmax, fmaxf(fmaxf(a.x, a.y), fmaxf(a.z, a.w)));
  }
  __shared__ unsigned bmin, bmax;
  if (threadIdx.x == 0) { bmin = 0xFFFFFFFFu; bmax = 0u; }
  __syncthreads();
  atomicMin(&bmin, fmono(lmin));
  atomicMax(&bmax, fmono(lmax));
  __syncthreads();
  if (threadIdx.x == 0) push_minmax(slots, bmin, bmax);
}

// ---------------- merged quantization + split prepass ----------------
// blocks [0,8192): Q (2,097,152 float4s); [8192,10240): K (16384 rows, 8/blk);
// [10240,10496): V (8 kvh x 32 dg)
#define PREP_QB 8192
#define PREP_KB 2048
#define PREP_VB 256
__global__ __launch_bounds__(256) void prep_kernel(const float* __restrict__ q,
    const float* __restrict__ k, const float* __restrict__ v,
    unsigned short* __restrict__ qnb, unsigned short* __restrict__ qh,
    unsigned short* __restrict__ ql,
    unsigned short* __restrict__ kzb, unsigned short* __restrict__ kmb,
    unsigned short* __restrict__ kh, unsigned short* __restrict__ kl,
    float* __restrict__ Zk, float* __restrict__ Mk,
    unsigned short* __restrict__ vzT, unsigned short* __restrict__ vmT,
    unsigned short* __restrict__ vhT, unsigned short* __restrict__ vlT,
    const float* __restrict__ cw) {
  const int b = blockIdx.x, tid = threadIdx.x;
  if (b < PREP_QB) {
    const float lo = cw[0], hi = cw[1], sc = cw[2];
    int idx = b * 256 + tid;
    float4 x = ((const float4*)q)[idx];
    float xa[4] = {x.x, x.y, x.z, x.w};
    ushort4 o, oh, ol;
    unsigned short* op = (unsigned short*)&o;
    unsigned short* ohp = (unsigned short*)&oh;
    unsigned short* olp = (unsigned short*)&ol;
#pragma unroll
    for (int j = 0; j < 4; ++j) {
      float n = rintf((fminf(fmaxf(xa[j], lo), hi) - lo) / sc);
      op[j] = f2bf(n);
      f16split(xa[j], &ohp[j], &olp[j]);
    }
    ((ushort4*)qnb)[idx] = o;
    ((ushort4*)qh)[idx] = oh;
    ((ushort4*)ql)[idx] = ol;
  } else if (b < PREP_QB + PREP_KB) {
    const float lo = cw[8], hi = cw[9], sc = cw[10], thr = cw[11];
    const int row = (b - PREP_QB) * 8 + (tid >> 5);
    const int c4 = (tid & 31) * 4;
    float4 x = *(const float4*)&k[(size_t)row * HD + c4];
    float xa[4] = {x.x, x.y, x.z, x.w};
    ushort4 zo, mo, ho, lo_;
    unsigned short* zp = (unsigned short*)&zo;
    unsigned short* mp = (unsigned short*)&mo;
    unsigned short* hp = (unsigned short*)&ho;
    unsigned short* lp = (unsigned short*)&lo_;
    float zs = 0.f, ms = 0.f;
#pragma unroll
    for (int j = 0; j < 4; ++j) {
      float m = rintf((fminf(fmaxf(xa[j], lo), hi) - lo) / sc);
      float kq = m * sc + lo;
      float z = (fabsf(kq) < thr) ? 0.f : 1.f;
      float mq = z * m;
      zs += z; ms += mq;
      zp[j] = f2bf(z); mp[j] = f2bf(mq);
      f16split(xa[j], &hp[j], &lp[j]);
    }
    *(ushort4*)&kzb[(size_t)row * HD + c4] = zo;
    *(ushort4*)&kmb[(size_t)row * HD + c4] = mo;
    *(ushort4*)&kh[(size_t)row * HD + c4] = ho;
    *(ushort4*)&kl[(size_t)row * HD + c4] = lo_;
#pragma unroll
    for (int off = 16; off > 0; off >>= 1) {
      zs += __shfl_xor(zs, off);
      ms += __shfl_xor(ms, off);
    }
    if ((tid & 31) == 0) { Zk[row] = zs; Mk[row] = ms; }
  } else {
    const float lo = cw[16], hi = cw[17], sc = cw[18], thr = cw[19];
    const int b2 = b - (PREP_QB + PREP_KB);
    const int kvh = b2 >> 5, dg = b2 & 31;
    for (int ch = 0; ch < 8; ++ch) {
      int kp = ch * 256 + tid;
      float4 x = *(const float4*)&v[((size_t)(kvh * SEQ + kp)) * HD + dg * 4];
      float xa[4] = {x.x, x.y, x.z, x.w};
#pragma unroll
      for (int j = 0; j < 4; ++j) {
        float m = rintf((fminf(fmaxf(xa[j], lo), hi) - lo) / sc);
        float vq = m * sc + lo;
        float z = (fabsf(vq) < thr) ? 0.f : 1.f;
        float mq = z * m;
        size_t o = ((size_t)(kvh * HD + dg * 4 + j)) * SEQ + kp;
        vzT[o] = f2bf(z);
        vmT[o] = f2bf(mq);
        unsigned short hb, lb;
        f16split(xa[j], &hb, &lb);
        vhT[o] = hb;
        vlT[o] = lb;
      }
    }
  }
}

// ---------------- QK raw min/max via 3-term fp16-split MFMA, LDS-staged B ----------------
__global__ __launch_bounds__(256, 2) void qk_raw_mfma(
    const unsigned short* __restrict__ qh, const unsigned short* __restrict__ ql,
    const unsigned short* __restrict__ kh, const unsigned short* __restrict__ kl,
    unsigned* __restrict__ slots) {
  __shared__ __align__(16) unsigned short s_h[128 * 128];
  __shared__ __align__(16) unsigned short s_l[128 * 128];
  const int kbi = blockIdx.x, qbi = blockIdx.y, h = blockIdx.z;
  const int kvh = h >> 2;
  const int tid = threadIdx.x;
  const int wid = tid >> 6, lane = tid & 63;
  const int fr = lane & 15, fg = lane >> 4;
  const int qrow0 = qbi * 128 + wid * 32;
  const int kcol0 = kbi * 128;
  const unsigned short* qhg = qh + (size_t)h * SEQ * HD;
  const unsigned short* qlg = ql + (size_t)h * SEQ * HD;

  stage_panel(kh + ((size_t)kvh * SEQ + kcol0) * HD, HD, s_h, tid);
  stage_panel(kl + ((size_t)kvh * SEQ + kcol0) * HD, HD, s_l, tid);
  __syncthreads();

  f32x4 acc[2][8];
  const f32x4 z4 = {0.f, 0.f, 0.f, 0.f};
#pragma unroll
  for (int rg = 0; rg < 2; ++rg)
#pragma unroll
    for (int cg = 0; cg < 8; ++cg) acc[rg][cg] = z4;

#pragma unroll
  for (int ks = 0; ks < 4; ++ks) {
    const int d0 = ks * 32 + fg * 8;
    const int c16 = ks * 4 + fg;
    const f16x8 a0h = *(const f16x8*)&qhg[(size_t)(qrow0 + fr) * HD + d0];
    const f16x8 a0l = *(const f16x8*)&qlg[(size_t)(qrow0 + fr) * HD + d0];
    const f16x8 a1h = *(const f16x8*)&qhg[(size_t)(qrow0 + 16 + fr) * HD + d0];
    const f16x8 a1l = *(const f16x8*)&qlg[(size_t)(qrow0 + 16 + fr) * HD + d0];
#pragma unroll
    for (int cg = 0; cg < 8; ++cg) {
      const f16x8 bh = frag_h(s_h, cg * 16 + fr, c16);
      const f16x8 bl = frag_h(s_l, cg * 16 + fr, c16);
      acc[0][cg] = __builtin_amdgcn_mfma_f32_16x16x32_f16(a0h, bh, acc[0][cg], 0, 0, 0);
      acc[0][cg] = __builtin_amdgcn_mfma_f32_16x16x32_f16(a0h, bl, acc[0][cg], 0, 0, 0);
      acc[0][cg] = __builtin_amdgcn_mfma_f32_16x16x32_f16(a0l, bh, acc[0][cg], 0, 0, 0);
      acc[1][cg] = __builtin_amdgcn_mfma_f32_16x16x32_f16(a1h, bh, acc[1][cg], 0, 0, 0);
      acc[1][cg] = __builtin_amdgcn_mfma_f32_16x16x32_f16(a1h, bl, acc[1][cg], 0, 0, 0);
      acc[1][cg] = __builtin_amdgcn_mfma_f32_16x16x32_f16(a1l, bh, acc[1][cg], 0, 0, 0);
    }
  }
  float lmin = INFINITY, lmax = -INFINITY;
#pragma unroll
  for (int rg = 0; rg < 2; ++rg)
#pragma unroll
    for (int cg = 0; cg < 8; ++cg)
#pragma unroll
      for (int r = 0; r < 4; ++r) {
        const float rv = acc[rg][cg][r] * SCALING_F;
        lmin = fminf(lmin, rv);
        lmax = fmaxf(lmax, rv);
      }
  __shared__ unsigned bmin, bmax;
  if (tid == 0) { bmin = 0xFFFFFFFFu; bmax = 0u; }
  __syncthreads();
  atomicMin(&bmin, fmono(lmin));
  atomicMax(&bmax, fmono(lmax));
  __syncthreads();
  if (tid == 0) push_minmax(slots, bmin, bmax);
}

// ---------------- QK quant (bf16 MFMA, exact integer grid), LDS-staged B ----------------
__global__ __launch_bounds__(256, 2) void qk_quant_kernel(
    const unsigned short* __restrict__ qnb, const unsigned short* __restrict__ kzb,
    const unsigned short* __restrict__ kmb, const float* __restrict__ Zk,
    const float* __restrict__ Mk, float* __restrict__ qdot,
    const float* __restrict__ cw) {
  const int kbi = blockIdx.x, qbi = blockIdx.y, h = blockIdx.z;
  if (kbi > qbi) return;            // raw-only region above the diagonal
  __shared__ __align__(16) unsigned short s_z[128 * 128];
  __shared__ __align__(16) unsigned short s_m[128 * 128];
  const int kvh = h >> 2;
  const float qlo = cw[0], qsc = cw[2];
  const float klo = cw[8], ksc = cw[10];
  const int tid = threadIdx.x;
  const int wid = tid >> 6, lane = tid & 63;
  const int fr = lane & 15, fg = lane >> 4;
  const int qrow0 = qbi * 128 + wid * 32;
  const int kcol0 = kbi * 128;
  const unsigned short* qg = qnb + (size_t)h * SEQ * HD;

  stage_panel(kzb + ((size_t)kvh * SEQ + kcol0) * HD, HD, s_z, tid);
  stage_panel(kmb + ((size_t)kvh * SEQ + kcol0) * HD, HD, s_m, tid);
  __syncthreads();

  f32x4 P[2][8], R[2][8];
  const f32x4 z4 = {0.f, 0.f, 0.f, 0.f};
#pragma unroll
  for (int rg = 0; rg < 2; ++rg)
#pragma unroll
    for (int cg = 0; cg < 8; ++cg) { P[rg][cg] = z4; R[rg][cg] = z4; }

#pragma unroll
  for (int ks = 0; ks < 4; ++ks) {
    const int d0 = ks * 32 + fg * 8;
    const int c16 = ks * 4 + fg;
    const bf16x8 a0 = *(const bf16x8*)&qg[(size_t)(qrow0 + fr) * HD + d0];
    const bf16x8 a1 = *(const bf16x8*)&qg[(size_t)(qrow0 + 16 + fr) * HD + d0];
#pragma unroll
    for (int cg = 0; cg < 8; ++cg) {
      const bf16x8 bz = frag_b(s_z, cg * 16 + fr, c16);
      const bf16x8 bm = frag_b(s_m, cg * 16 + fr, c16);
      P[0][cg] = __builtin_amdgcn_mfma_f32_16x16x32_bf16(a0, bz, P[0][cg], 0, 0, 0);
      P[1][cg] = __builtin_amdgcn_mfma_f32_16x16x32_bf16(a1, bz, P[1][cg], 0, 0, 0);
      R[0][cg] = __builtin_amdgcn_mfma_f32_16x16x32_bf16(a0, bm, R[0][cg], 0, 0, 0);
      R[1][cg] = __builtin_amdgcn_mfma_f32_16x16x32_bf16(a1, bm, R[1][cg], 0, 0, 0);
    }
  }
#pragma unroll
  for (int cg = 0; cg < 8; ++cg) {
    const int col = kcol0 + cg * 16 + fr;
    const float Z = Zk[kvh * SEQ + col], M = Mk[kvh * SEQ + col];
    const float base = qlo * (klo * Z + ksc * M);
#pragma unroll
    for (int rg = 0; rg < 2; ++rg)
#pragma unroll
      for (int r = 0; r < 4; ++r) {
        const int row = qrow0 + rg * 16 + fg * 4 + r;
        qdot[((size_t)h * SEQ + row) * SEQ + col] =
            base + qsc * (klo * P[rg][cg][r] + ksc * R[rg][cg][r]);
      }
  }
}

// ---------------- softmax: causal skip + stoch-quant + softmax ----------------
__global__ __launch_bounds__(256) void softmax_kernel(
    float* __restrict__ attn, const float* __restrict__ cw,
    unsigned* __restrict__ slots, uint32_t uk0, uint32_t uk1) {
  const int row = blockIdx.x;          // h*SEQ + qi
  const int qi = row & (SEQ - 1);
  const int tid = threadIdx.x;
  const float lo = cw[24], hi = cw[25], sc = cw[26], sci = cw[28];
  float* prow = attn + (size_t)row * SEQ;
  const uint32_t jbase = (uint32_t)row << 11;

  float vals[8];
  float lmax = -INFINITY;
#pragma unroll
  for (int m = 0; m < 2; ++m) {
    int ki = m * 1024 + tid * 4;
    if (ki <= qi) {
      float4 x4 = *(const float4*)&prow[ki];
      float xa[4] = {x4.x, x4.y, x4.z, x4.w};
#pragma unroll
      for (int j = 0; j < 4; ++j) {
        if (ki + j <= qi) {
          float u = tf_uniform(uk0, uk1, jbase + (uint32_t)(ki + j));
          float lg = fq_st_i(xa[j], lo, hi, sc, sci, u) * SCALING_F;
          vals[m * 4 + j] = lg;
          lmax = fmaxf(lmax, lg);
        } else {
          vals[m * 4 + j] = -INFINITY;
        }
      }
    } else {
      vals[m * 4 + 0] = vals[m * 4 + 1] = vals[m * 4 + 2] = vals[m * 4 + 3] = -INFINITY;
    }
  }

  __shared__ float smax[4], ssum[4], smn[4], smx[4];
#pragma unroll
  for (int off = 32; off > 0; off >>= 1) lmax = fmaxf(lmax, __shfl_xor(lmax, off));
  if ((tid & 63) == 0) smax[tid >> 6] = lmax;
  __syncthreads();
  float rmax = fmaxf(fmaxf(smax[0], smax[1]), fmaxf(smax[2], smax[3]));

  float lsum = 0.f;
#pragma unroll
  for (int e = 0; e < 8; ++e) { vals[e] = __expf(vals[e] - rmax); lsum += vals[e]; }
#pragma unroll
  for (int off = 32; off > 0; off >>= 1) lsum += __shfl_xor(lsum, off);
  if ((tid & 63) == 0) ssum[tid >> 6] = lsum;
  __syncthreads();
  float rinv = 1.0f / (ssum[0] + ssum[1] + ssum[2] + ssum[3]);

  float lmin2 = INFINITY, lmax2 = -INFINITY;
#pragma unroll
  for (int m = 0; m < 2; ++m) {
    int ki = m * 1024 + tid * 4;
    float4 st;
    float* stp = (float*)&st;
#pragma unroll
    for (int j = 0; j < 4; ++j) {
      float w = vals[m * 4 + j] * rinv;
      stp[j] = w;
      lmin2 = fminf(lmin2, w);
      lmax2 = fmaxf(lmax2, w);
    }
    *(float4*)&prow[ki] = st;
  }
#pragma unroll
  for (int off = 32; off > 0; off >>= 1) {
    lmin2 = fminf(lmin2, __shfl_xor(lmin2, off));
    lmax2 = fmaxf(lmax2, __shfl_xor(lmax2, off));
  }
  if ((tid & 63) == 0) { smn[tid >> 6] = lmin2; smx[tid >> 6] = lmax2; }
  __syncthreads();
  if (tid == 0) {
    float mn = fminf(fminf(smn[0], smn[1]), fminf(smn[2], smn[3]));
    float mx = fmaxf(fmaxf(smx[0], smx[1]), fmaxf(smx[2], smx[3]));
    push_minmax(slots, fmono(mn), fmono(mx));
  }
}

// ---------------- packers ----------------
__device__ __forceinline__ void pack_split8(const float* __restrict__ p,
                                            f16x8* ah, f16x8* al) {
  float4 w0 = *(const float4*)p;
  float4 w1 = *(const float4*)(p + 4);
  float wa[8] = {w0.x, w0.y, w0.z, w0.w, w1.x, w1.y, w1.z, w1.w};
  f16x8 h, l;
#pragma unroll
  for (int j = 0; j < 8; ++j) {
    _Float16 hf = (_Float16)wa[j];
    h[j] = hf;
    l[j] = (_Float16)(wa[j] - (float)hf);
  }
  *ah = h; *al = l;
}

__device__ __forceinline__ bf16x8 pack_a8(const float* __restrict__ ar,
                                          float lo, float hi, float sc) {
  float4 w0 = *(const float4*)ar;
  float4 w1 = *(const float4*)(ar + 4);
  float wa[8] = {w0.x, w0.y, w0.z, w0.w, w1.x, w1.y, w1.z, w1.w};
  bf16x8 r;
#pragma unroll
  for (int j = 0; j < 8; ++j) {
    float n = rintf((fminf(fmaxf(wa[j], lo), hi) - lo) / sc);
    r[j] = (short)(__float_as_uint(n) >> 16);
  }
  return r;
}

// ---------------- AV raw (3-term f16 MFMA), LDS-staged V ----------------
__global__ __launch_bounds__(256, 2) void av_raw_mfma(
    const float* __restrict__ attn, const unsigned short* __restrict__ vhT,
    const unsigned short* __restrict__ vlT, unsigned* __restrict__ slots) {
  __shared__ __align__(16) unsigned short s_h[128 * 128];
  __shared__ __align__(16) unsigned short s_l[128 * 128];
  const int qbi = (int)gridDim.x - 1 - (int)blockIdx.x;  // largest blocks first
  const int h = blockIdx.y, kvh = h >> 2;
  const int tid = threadIdx.x;
  const int wid = tid >> 6, lane = tid & 63;
  const int fr = lane & 15, fg = lane >> 4;
  const int qrow0 = qbi * 128 + wid * 32;
  const float* ag = attn + (size_t)h * SEQ * SEQ;
  const unsigned short* bhg = vhT + (size_t)kvh * HD * SEQ;
  const unsigned short* blg = vlT + (size_t)kvh * HD * SEQ;
  const int nc = qbi + 1;   // 128-kp chunks; beyond qb+127 attn is exactly 0
  f32x4 acc[2][8];
  const f32x4 z4 = {0.f, 0.f, 0.f, 0.f};
#pragma unroll
  for (int rg = 0; rg < 2; ++rg)
#pragma unroll
    for (int cg = 0; cg < 8; ++cg) acc[rg][cg] = z4;

  for (int c = 0; c < nc; ++c) {
    __syncthreads();
    stage_panel(bhg + c * 128, SEQ, s_h, tid);
    stage_panel(blg + c * 128, SEQ, s_l, tid);
    __syncthreads();
#pragma unroll
    for (int ks = 0; ks < 4; ++ks) {
      const int kp0 = c * 128 + ks * 32 + fg * 8;
      const int c16 = ks * 4 + fg;
      f16x8 a0h, a0l, a1h, a1l;
      pack_split8(ag + (size_t)(qrow0 + fr) * SEQ + kp0, &a0h, &a0l);
      pack_split8(ag + (size_t)(qrow0 + 16 + fr) * SEQ + kp0, &a1h, &a1l);
#pragma unroll
      for (int cg = 0; cg < 8; ++cg) {
        const f16x8 bh = frag_h(s_h, cg * 16 + fr, c16);
        const f16x8 bl = frag_h(s_l, cg * 16 + fr, c16);
        acc[0][cg] = __builtin_amdgcn_mfma_f32_16x16x32_f16(a0h, bh, acc[0][cg], 0, 0, 0);
        acc[0][cg] = __builtin_amdgcn_mfma_f32_16x16x32_f16(a0h, bl, acc[0][cg], 0, 0, 0);
        acc[0][cg] = __builtin_amdgcn_mfma_f32_16x16x32_f16(a0l, bh, acc[0][cg], 0, 0, 0);
        acc[1][cg] = __builtin_amdgcn_mfma_f32_16x16x32_f16(a1h, bh, acc[1][cg], 0, 0, 0);
        acc[1][cg] = __builtin_amdgcn_mfma_f32_16x16x32_f16(a1h, bl, acc[1][cg], 0, 0, 0);
        acc[1][cg] = __builtin_amdgcn_mfma_f32_16x16x32_f16(a1l, bh, acc[1][cg], 0, 0, 0);
      }
    }
  }
  float lmin = INFINITY, lmax = -INFINITY;
#pragma unroll
  for (int rg = 0; rg < 2; ++rg)
#pragma unroll
    for (int cg = 0; cg < 8; ++cg)
#pragma unroll
      for (int r = 0; r < 4; ++r) {
        lmin = fminf(lmin, acc[rg][cg][r]);
        lmax = fmaxf(lmax, acc[rg][cg][r]);
      }
  __shared__ unsigned bmin, bmax;
  if (tid == 0) { bmin = 0xFFFFFFFFu; bmax = 0u; }
  __syncthreads();
  atomicMin(&bmin, fmono(lmin));
  atomicMax(&bmax, fmono(lmax));
  __syncthreads();
  if (tid == 0) push_minmax(slots, bmin, bmax);
}

// ---------------- AV quant + fused final stochastic quantization ----------------
// Runs after finalize(av) so cw[40..44] is final; applies the stoch step in the
// epilogue (bit-identical to the former separate stoch pass; j index matches).
__global__ __launch_bounds__(256, 2) void av_quant_kernel(
    const float* __restrict__ attn, const unsigned short* __restrict__ vzT,
    const unsigned short* __restrict__ vmT, float* __restrict__ out0,
    const float* __restrict__ cw, uint32_t uk0, uint32_t uk1) {
  __shared__ __align__(16) unsigned short s_z[128 * 128];
  __shared__ __align__(16) unsigned short s_m[128 * 128];
  const int qbi = (int)gridDim.x - 1 - (int)blockIdx.x;
  const int h = blockIdx.y, kvh = h >> 2;
  const float alo = cw[32], ahi = cw[33], asc = cw[34];
  const float vlo = cw[16], vsc = cw[18];
  const float slo = cw[40], shi = cw[41], ssc = cw[42], ssci = cw[44];
  const int tid = threadIdx.x;
  const int wid = tid >> 6, lane = tid & 63;
  const int fr = lane & 15, fg = lane >> 4;
  const int qrow0 = qbi * 128 + wid * 32;
  const float* ag = attn + (size_t)h * SEQ * SEQ;
  const unsigned short* zg = vzT + (size_t)kvh * HD * SEQ;
  const unsigned short* mg = vmT + (size_t)kvh * HD * SEQ;
  const int nc = qbi + 1;
  f32x4 P[2][8], R[2][8];
  const f32x4 z4 = {0.f, 0.f, 0.f, 0.f};
#pragma unroll
  for (int rg = 0; rg < 2; ++rg)
#pragma unroll
    for (int cg = 0; cg < 8; ++cg) { P[rg][cg] = z4; R[rg][cg] = z4; }

  for (int c = 0; c < nc; ++c) {
    __syncthreads();
    stage_panel(zg + c * 128, SEQ, s_z, tid);
    stage_panel(mg + c * 128, SEQ, s_m, tid);
    __syncthreads();
#pragma unroll
    for (int ks = 0; ks < 4; ++ks) {
      const int kp0 = c * 128 + ks * 32 + fg * 8;
      const int c16 = ks * 4 + fg;
      const bf16x8 a0 = pack_a8(ag + (size_t)(qrow0 + fr) * SEQ + kp0, alo, ahi, asc);
      const bf16x8 a1 = pack_a8(ag + (size_t)(qrow0 + 16 + fr) * SEQ + kp0, alo, ahi, asc);
#pragma unroll
      for (int cg = 0; cg < 8; ++cg) {
        const bf16x8 bz = frag_b(s_z, cg * 16 + fr, c16);
        const bf16x8 bm = frag_b(s_m, cg * 16 + fr, c16);
        P[0][cg] = __builtin_amdgcn_mfma_f32_16x16x32_bf16(a0, bz, P[0][cg], 0, 0, 0);
        P[1][cg] = __builtin_amdgcn_mfma_f32_16x16x32_bf16(a1, bz, P[1][cg], 0, 0, 0);
        R[0][cg] = __builtin_amdgcn_mfma_f32_16x16x32_bf16(a0, bm, R[0][cg], 0, 0, 0);
        R[1][cg] = __builtin_amdgcn_mfma_f32_16x16x32_bf16(a1, bm, R[1][cg], 0, 0, 0);
      }
    }
  }
#pragma unroll
  for (int cg = 0; cg < 8; ++cg) {
    const int dcol = cg * 16 + fr;
#pragma unroll
    for (int rg = 0; rg < 2; ++rg)
#pragma unroll
      for (int r = 0; r < 4; ++r) {
        const int row = qrow0 + rg * 16 + fg * 4 + r;
        const float val = asc * (vlo * P[rg][cg][r] + vsc * R[rg][cg][r]);
        const uint32_t j = ((uint32_t)h * SEQ + (uint32_t)row) * HD + (uint32_t)dcol;
        const float u = tf_uniform(uk0, uk1, j);
        out0[((size_t)row * NH + h) * HD + dcol] = fq_st_i(val, slo, shi, ssc, ssci, u);
      }
  }
}

// ---------------- launcher ----------------
extern "C" void kernel_launch(void* const* d_in, const int* in_sizes, int n_in,
                              void* d_out, int out_size, void* d_ws, size_t ws_size,
                              hipStream_t stream) {
  (void)in_sizes; (void)n_in; (void)out_size; (void)ws_size;
  const float* q      = (const float*)d_in[0];
  const float* k      = (const float*)d_in[1];
  const float* v      = (const float*)d_in[2];
  const float* q_old  = (const float*)d_in[4];
  const float* k_old  = (const float*)d_in[5];
  const float* qk_old = (const float*)d_in[6];
  const float* a_old  = (const float*)d_in[7];
  const float* v_old  = (const float*)d_in[8];
  const float* av_old = (const float*)d_in[9];
  float* out0 = (float*)d_out;
  float* out1 = out0 + (size_t)OUT0_N;
  unsigned* su = (unsigned*)d_ws;
  float* cw = (float*)d_ws + 16;

  // d_ws scratch: vzT/vmT (live until av_quant), Zk/Mk  (~8.5 MB)
  unsigned short* vzT = (unsigned short*)((char*)d_ws + 1024);
  unsigned short* vmT = vzT + (size_t)NKVH * SEQ * HD;
  float* Zk = (float*)(vmT + (size_t)NKVH * SEQ * HD);
  float* Mk = Zk + NKVH * SEQ;

  // out0-region scratch (exactly fills 32 MB; all consumed before av_quant
  // overwrites out0): qnb(16MB) kzb(4MB) kmb(4MB) vhT(4MB) vlT(4MB)
  unsigned short* qnb = (unsigned short*)out0;
  unsigned short* kzb = qnb + (size_t)NH * SEQ * HD;
  unsigned short* kmb = kzb + (size_t)NKVH * SEQ * HD;
  unsigned short* vhT = kmb + (size_t)NKVH * SEQ * HD;
  unsigned short* vlT = vhT + (size_t)NKVH * SEQ * HD;

  // out1-region scratch (consumed by qk_raw_mfma before qk_quant writes out1)
  unsigned short* qh = (unsigned short*)out1;
  unsigned short* ql = qh + (size_t)NH * SEQ * HD;
  unsigned short* kh = ql + (size_t)NH * SEQ * HD;
  unsigned short* kl = kh + (size_t)NKVH * SEQ * HD;

  uint32_t kq0, kq1, ka0, ka1;
  tf2x32(0u, 0u, 0u, 0u, &kq0, &kq1);
  tf2x32(0u, 0u, 0u, 1u, &ka0, &ka1);

  init_ws<<<1, 32, 0, stream>>>(su);
  minmax3_kernel<<<2048, 256, 0, stream>>>((const float4*)q, (const float4*)k,
                                           (const float4*)v, su);
  finalize3_kernel<<<1, 32, 0, stream>>>(su, q_old, k_old, v_old, cw);
  prep_kernel<<<PREP_QB + PREP_KB + PREP_VB, 256, 0, stream>>>(
      q, k, v, qnb, qh, ql, kzb, kmb, kh, kl, Zk, Mk, vzT, vmT, vhT, vlT, cw);

  qk_raw_mfma<<<dim3(16, 16, NH), 256, 0, stream>>>(qh, ql, kh, kl, su + 6);
  finalize_kernel<<<1, 1, 0, stream>>>(su + 6, qk_old, cw + 24);
  qk_quant_kernel<<<dim3(16, 16, NH), 256, 0, stream>>>(qnb, kzb, kmb, Zk, Mk, out1, cw);

  softmax_kernel<<<NH * SEQ, 256, 0, stream>>>(out1, cw, su + 8, kq0, kq1);
  finalize_kernel<<<1, 1, 0, stream>>>(su + 8, a_old, cw + 32);

  av_raw_mfma<<<dim3(16, NH), 256, 0, stream>>>(out1, vhT, vlT, su + 10);
  finalize_kernel<<<1, 1, 0, stream>>>(su + 10, av_old, cw + 40);
  av_quant_kernel<<<dim3(16, NH), 256, 0, stream>>>(out1, vzT, vmT, out0, cw, ka0, ka1);
}

// Round 8
// 1521.755 us; speedup vs baseline: 1.1551x; 1.0271x over previous
//
#include <hip/hip_runtime.h>
#include <stdint.h>
#include <math.h>

#pragma clang fp contract(off)

#define NH 32
#define NKVH 8
#define SEQ 2048
#define HD 128
#define SCALING_F 0.08838834764831845f
#define OUT0_N (SEQ*NH*HD)   /* 8388608 */

typedef __attribute__((ext_vector_type(8))) short bf16x8;      // 8 bf16 = 4 VGPRs
typedef __attribute__((ext_vector_type(8))) _Float16 f16x8;    // 8 f16  = 4 VGPRs
typedef __attribute__((ext_vector_type(8))) unsigned short u16x8;
typedef __attribute__((ext_vector_type(4))) float f32x4;

// ---------------- threefry2x32 (JAX-compatible) ----------------
__host__ __device__ __forceinline__ void tf2x32(uint32_t k0, uint32_t k1,
    uint32_t x0, uint32_t x1, uint32_t* o0, uint32_t* o1) {
  uint32_t k2 = k0 ^ k1 ^ 0x1BD11BDAu;
  x0 += k0; x1 += k1;
#define TFR(r) { x0 += x1; x1 = (x1 << (r)) | (x1 >> (32 - (r))); x1 ^= x0; }
  TFR(13) TFR(15) TFR(26) TFR(6)
  x0 += k1; x1 += k2 + 1u;
  TFR(17) TFR(29) TFR(16) TFR(24)
  x0 += k2; x1 += k0 + 2u;
  TFR(13) TFR(15) TFR(26) TFR(6)
  x0 += k0; x1 += k1 + 3u;
  TFR(17) TFR(29) TFR(16) TFR(24)
  x0 += k1; x1 += k2 + 4u;
  TFR(13) TFR(15) TFR(26) TFR(6)
  x0 += k2; x1 += k0 + 5u;
#undef TFR
  *o0 = x0; *o1 = x1;
}

__device__ __forceinline__ float tf_uniform(uint32_t k0, uint32_t k1, uint32_t idx) {
  uint32_t a, b;
  tf2x32(k0, k1, 0u, idx, &a, &b);
  uint32_t bits = a ^ b;
  return __uint_as_float((bits >> 9) | 0x3f800000u) - 1.0f;
}

// ---------------- monotone float<->uint for atomic min/max ----------------
__device__ __forceinline__ unsigned fmono(float x) {
  unsigned u = __float_as_uint(x);
  return (u >> 31) ? ~u : (u | 0x80000000u);
}
__device__ __forceinline__ float funmono(unsigned m) {
  return __uint_as_float((m >> 31) ? (m ^ 0x80000000u) : ~m);
}

__device__ __forceinline__ void push_minmax(unsigned* slots, unsigned cm, unsigned cM) {
  volatile unsigned* vs = (volatile unsigned*)slots;
  if (cm < vs[0]) atomicMin(&slots[0], cm);
  if (cM > vs[1]) atomicMax(&slots[1], cM);
}

// bf16 truncation — exact for integer values <= 256 (our only use)
__device__ __forceinline__ unsigned short f2bf(float x) {
  return (unsigned short)(__float_as_uint(x) >> 16);
}

// fp16 hi/lo split: x ~= hi + lo with residual <= 2^-23 |x|
__device__ __forceinline__ void f16split(float x, unsigned short* h, unsigned short* l) {
  _Float16 hf = (_Float16)x;
  float r = x - (float)hf;         // exact (Sterbenz)
  _Float16 lf = (_Float16)r;
  *h = __builtin_bit_cast(unsigned short, hf);
  *l = __builtin_bit_cast(unsigned short, lf);
}

__device__ __forceinline__ float fq_st_i(float x, float lo, float hi, float scale,
                                         float scinv, float u) {
  float c = fminf(fmaxf(x, lo), hi);
  float t = (c - lo) * scinv;
  return floorf(t + u) * scale + lo;
}

// ---------------- swizzled LDS panel helpers ----------------
// 128-wide panel: [128 rows][128 2B], row stride 256B.
#define SWZ_OFF(row, c16) ((((row) * 256) + ((c16) * 16)) ^ (((row) & 7) << 4))

__device__ __forceinline__ void stage_panel(const unsigned short* __restrict__ g,
                                            int rowstride, unsigned short* s, int tid) {
#pragma unroll
  for (int it = 0; it < 8; ++it) {
    const int i = it * 256 + tid;
    const int row = i >> 4, c16 = i & 15;
    const u16x8 val = *(const u16x8*)&g[(size_t)row * rowstride + c16 * 8];
    *(u16x8*)((char*)s + SWZ_OFF(row, c16)) = val;
  }
}

__device__ __forceinline__ f16x8 frag_h(const unsigned short* s, int row, int c16) {
  return *(const f16x8*)((const char*)s + SWZ_OFF(row, c16));
}
__device__ __forceinline__ bf16x8 frag_b(const unsigned short* s, int row, int c16) {
  return *(const bf16x8*)((const char*)s + SWZ_OFF(row, c16));
}

// ---------------- tiny kernels ----------------
__global__ void init_ws(unsigned* su) {
  int t = threadIdx.x;
  if (t < 12) su[t] = (t & 1) ? 0u : 0xFFFFFFFFu;
}

// cw stat block stride 8: [lo, hi, scale, lut_thr, inv_scale, _, _, _]
__device__ __forceinline__ void finalize_one(const unsigned* slots,
                                             const float* oldmm, float* outc) {
  float clo = funmono(slots[0]), chi = funmono(slots[1]);
  float o0 = oldmm[0], o1 = oldmm[1];
  bool fin = isfinite(o0) && isfinite(o1);
  float lo = fin ? (0.9f * o0 + 0.1f * clo) : clo;
  float hi = fin ? (0.9f * o1 + 0.1f * chi) : chi;
  float sc = (hi - lo) / 255.0f;
  outc[0] = lo;
  outc[1] = hi;
  outc[2] = sc;
  outc[3] = 0.02004f * fmaxf(fabsf(lo), fabsf(hi));
  outc[4] = 1.0f / sc;
}

__global__ void finalize_kernel(const unsigned* __restrict__ slots,
                                const float* __restrict__ oldmm,
                                float* __restrict__ outc) {
  if (threadIdx.x == 0) finalize_one(slots, oldmm, outc);
}

__global__ void finalize3_kernel(const unsigned* __restrict__ su,
                                 const float* __restrict__ q_old,
                                 const float* __restrict__ k_old,
                                 const float* __restrict__ v_old,
                                 float* __restrict__ cw) {
  int t = threadIdx.x;
  if (t == 0) finalize_one(su + 0, q_old, cw + 0);
  else if (t == 1) finalize_one(su + 2, k_old, cw + 8);
  else if (t == 2) finalize_one(su + 4, v_old, cw + 16);
}

// one launch for q/k/v input min/max: blocks [0,1024)=q, [1024,1536)=k, [1536,2048)=v
__global__ __launch_bounds__(256) void minmax3_kernel(const float4* __restrict__ q,
    const float4* __restrict__ k, const float4* __restrict__ v,
    unsigned* __restrict__ su) {
  const int b = blockIdx.x;
  const float4* x;
  int n4, b0, nb;
  unsigned* slots;
  if (b < 1024) { x = q; n4 = (NH * SEQ * HD) / 4; b0 = 0; nb = 1024; slots = su + 0; }
  else if (b < 1536) { x = k; n4 = (NKVH * SEQ * HD) / 4; b0 = 1024; nb = 512; slots = su + 2; }
  else { x = v; n4 = (NKVH * SEQ * HD) / 4; b0 = 1536; nb = 512; slots = su + 4; }
  float lmin = INFINITY, lmax = -INFINITY;
  for (int i = (b - b0) * 256 + threadIdx.x; i < n4; i += nb * 256) {
    float4 a = x[i];
    lmin = fminf(lmin, fminf(fminf(a.x, a.y), fminf(a.z, a.w)));
    lmax = fmaxf(lmax, fmaxf(fmaxf(a.x, a.y), fmaxf(a.z, a.w)));
  }
  __shared__ unsigned bmin, bmax;
  if (threadIdx.x == 0) { bmin = 0xFFFFFFFFu; bmax = 0u; }
  __syncthreads();
  atomicMin(&bmin, fmono(lmin));
  atomicMax(&bmax, fmono(lmax));
  __syncthreads();
  if (threadIdx.x == 0) push_minmax(slots, bmin, bmax);
}

// ---------------- merged quantization + split prepass ----------------
// blocks [0,8192): Q; [8192,10240): K (16384 rows, 8/blk); [10240,10496): V
#define PREP_QB 8192
#define PREP_KB 2048
#define PREP_VB 256
__global__ __launch_bounds__(256) void prep_kernel(const float* __restrict__ q,
    const float* __restrict__ k, const float* __restrict__ v,
    unsigned short* __restrict__ qnb, unsigned short* __restrict__ qh,
    unsigned short* __restrict__ ql,
    unsigned short* __restrict__ kzb, unsigned short* __restrict__ kmb,
    unsigned short* __restrict__ kh, unsigned short* __restrict__ kl,
    float* __restrict__ Zk, float* __restrict__ Mk,
    unsigned short* __restrict__ vzT, unsigned short* __restrict__ vmT,
    unsigned short* __restrict__ vhT, unsigned short* __restrict__ vlT,
    const float* __restrict__ cw) {
  const int b = blockIdx.x, tid = threadIdx.x;
  if (b < PREP_QB) {
    const float lo = cw[0], hi = cw[1], sc = cw[2];
    int idx = b * 256 + tid;
    float4 x = ((const float4*)q)[idx];
    float xa[4] = {x.x, x.y, x.z, x.w};
    ushort4 o, oh, ol;
    unsigned short* op = (unsigned short*)&o;
    unsigned short* ohp = (unsigned short*)&oh;
    unsigned short* olp = (unsigned short*)&ol;
#pragma unroll
    for (int j = 0; j < 4; ++j) {
      float n = rintf((fminf(fmaxf(xa[j], lo), hi) - lo) / sc);
      op[j] = f2bf(n);
      f16split(xa[j], &ohp[j], &olp[j]);
    }
    ((ushort4*)qnb)[idx] = o;
    ((ushort4*)qh)[idx] = oh;
    ((ushort4*)ql)[idx] = ol;
  } else if (b < PREP_QB + PREP_KB) {
    const float lo = cw[8], hi = cw[9], sc = cw[10], thr = cw[11];
    const int row = (b - PREP_QB) * 8 + (tid >> 5);
    const int c4 = (tid & 31) * 4;
    float4 x = *(const float4*)&k[(size_t)row * HD + c4];
    float xa[4] = {x.x, x.y, x.z, x.w};
    ushort4 zo, mo, ho, lo_;
    unsigned short* zp = (unsigned short*)&zo;
    unsigned short* mp = (unsigned short*)&mo;
    unsigned short* hp = (unsigned short*)&ho;
    unsigned short* lp = (unsigned short*)&lo_;
    float zs = 0.f, ms = 0.f;
#pragma unroll
    for (int j = 0; j < 4; ++j) {
      float m = rintf((fminf(fmaxf(xa[j], lo), hi) - lo) / sc);
      float kq = m * sc + lo;
      float z = (fabsf(kq) < thr) ? 0.f : 1.f;
      float mq = z * m;
      zs += z; ms += mq;
      zp[j] = f2bf(z); mp[j] = f2bf(mq);
      f16split(xa[j], &hp[j], &lp[j]);
    }
    *(ushort4*)&kzb[(size_t)row * HD + c4] = zo;
    *(ushort4*)&kmb[(size_t)row * HD + c4] = mo;
    *(ushort4*)&kh[(size_t)row * HD + c4] = ho;
    *(ushort4*)&kl[(size_t)row * HD + c4] = lo_;
#pragma unroll
    for (int off = 16; off > 0; off >>= 1) {
      zs += __shfl_xor(zs, off);
      ms += __shfl_xor(ms, off);
    }
    if ((tid & 31) == 0) { Zk[row] = zs; Mk[row] = ms; }
  } else {
    const float lo = cw[16], hi = cw[17], sc = cw[18], thr = cw[19];
    const int b2 = b - (PREP_QB + PREP_KB);
    const int kvh = b2 >> 5, dg = b2 & 31;
    for (int ch = 0; ch < 8; ++ch) {
      int kp = ch * 256 + tid;
      float4 x = *(const float4*)&v[((size_t)(kvh * SEQ + kp)) * HD + dg * 4];
      float xa[4] = {x.x, x.y, x.z, x.w};
#pragma unroll
      for (int j = 0; j < 4; ++j) {
        float m = rintf((fminf(fmaxf(xa[j], lo), hi) - lo) / sc);
        float vq = m * sc + lo;
        float z = (fabsf(vq) < thr) ? 0.f : 1.f;
        float mq = z * m;
        size_t o = ((size_t)(kvh * HD + dg * 4 + j)) * SEQ + kp;
        vzT[o] = f2bf(z);
        vmT[o] = f2bf(mq);
        unsigned short hb, lb;
        f16split(xa[j], &hb, &lb);
        vhT[o] = hb;
        vlT[o] = lb;
      }
    }
  }
}

// ---------------- QK raw min/max via 3-term fp16-split MFMA ----------------
// 256-row q-tile per block (64 rows/wave = 4 rowgroups): each staged K-frag
// feeds 12 MFMAs instead of 6 -> LDS-pipe oversubscription 3.2x -> 1.6x.
// Bit-identical accumulation per output element vs the 128-row tiling.
__global__ __launch_bounds__(256, 2) void qk_raw_mfma(
    const unsigned short* __restrict__ qh, const unsigned short* __restrict__ ql,
    const unsigned short* __restrict__ kh, const unsigned short* __restrict__ kl,
    unsigned* __restrict__ slots) {
  __shared__ __align__(16) unsigned short s_h[128 * 128];
  __shared__ __align__(16) unsigned short s_l[128 * 128];
  const int kbi = blockIdx.x, qbi = blockIdx.y, h = blockIdx.z;
  const int kvh = h >> 2;
  const int tid = threadIdx.x;
  const int wid = tid >> 6, lane = tid & 63;
  const int fr = lane & 15, fg = lane >> 4;
  const int qrow0 = qbi * 256 + wid * 64;
  const int kcol0 = kbi * 128;
  const unsigned short* qhg = qh + (size_t)h * SEQ * HD;
  const unsigned short* qlg = ql + (size_t)h * SEQ * HD;

  stage_panel(kh + ((size_t)kvh * SEQ + kcol0) * HD, HD, s_h, tid);
  stage_panel(kl + ((size_t)kvh * SEQ + kcol0) * HD, HD, s_l, tid);
  __syncthreads();

  f32x4 acc[4][8];
  const f32x4 z4 = {0.f, 0.f, 0.f, 0.f};
#pragma unroll
  for (int rg = 0; rg < 4; ++rg)
#pragma unroll
    for (int cg = 0; cg < 8; ++cg) acc[rg][cg] = z4;

#pragma unroll 1
  for (int ks = 0; ks < 4; ++ks) {
    const int d0 = ks * 32 + fg * 8;
    const int c16 = ks * 4 + fg;
    f16x8 ah[4], al[4];
#pragma unroll
    for (int rg = 0; rg < 4; ++rg) {
      ah[rg] = *(const f16x8*)&qhg[(size_t)(qrow0 + rg * 16 + fr) * HD + d0];
      al[rg] = *(const f16x8*)&qlg[(size_t)(qrow0 + rg * 16 + fr) * HD + d0];
    }
#pragma unroll
    for (int cg = 0; cg < 8; ++cg) {
      const f16x8 bh = frag_h(s_h, cg * 16 + fr, c16);
      const f16x8 bl = frag_h(s_l, cg * 16 + fr, c16);
#pragma unroll
      for (int rg = 0; rg < 4; ++rg) {
        acc[rg][cg] = __builtin_amdgcn_mfma_f32_16x16x32_f16(ah[rg], bh, acc[rg][cg], 0, 0, 0);
        acc[rg][cg] = __builtin_amdgcn_mfma_f32_16x16x32_f16(ah[rg], bl, acc[rg][cg], 0, 0, 0);
        acc[rg][cg] = __builtin_amdgcn_mfma_f32_16x16x32_f16(al[rg], bh, acc[rg][cg], 0, 0, 0);
      }
    }
  }
  float lmin = INFINITY, lmax = -INFINITY;
#pragma unroll
  for (int rg = 0; rg < 4; ++rg)
#pragma unroll
    for (int cg = 0; cg < 8; ++cg)
#pragma unroll
      for (int r = 0; r < 4; ++r) {
        const float rv = acc[rg][cg][r] * SCALING_F;
        lmin = fminf(lmin, rv);
        lmax = fmaxf(lmax, rv);
      }
  __shared__ unsigned bmin, bmax;
  if (tid == 0) { bmin = 0xFFFFFFFFu; bmax = 0u; }
  __syncthreads();
  atomicMin(&bmin, fmono(lmin));
  atomicMax(&bmax, fmono(lmax));
  __syncthreads();
  if (tid == 0) push_minmax(slots, bmin, bmax);
}

// ---------------- QK quant (bf16 MFMA, exact integer grid), LDS-staged B ----------------
__global__ __launch_bounds__(256, 2) void qk_quant_kernel(
    const unsigned short* __restrict__ qnb, const unsigned short* __restrict__ kzb,
    const unsigned short* __restrict__ kmb, const float* __restrict__ Zk,
    const float* __restrict__ Mk, float* __restrict__ qdot,
    const float* __restrict__ cw) {
  const int kbi = blockIdx.x, qbi = blockIdx.y, h = blockIdx.z;
  if (kbi > qbi) return;            // raw-only region above the diagonal
  __shared__ __align__(16) unsigned short s_z[128 * 128];
  __shared__ __align__(16) unsigned short s_m[128 * 128];
  const int kvh = h >> 2;
  const float qlo = cw[0], qsc = cw[2];
  const float klo = cw[8], ksc = cw[10];
  const int tid = threadIdx.x;
  const int wid = tid >> 6, lane = tid & 63;
  const int fr = lane & 15, fg = lane >> 4;
  const int qrow0 = qbi * 128 + wid * 32;
  const int kcol0 = kbi * 128;
  const unsigned short* qg = qnb + (size_t)h * SEQ * HD;

  stage_panel(kzb + ((size_t)kvh * SEQ + kcol0) * HD, HD, s_z, tid);
  stage_panel(kmb + ((size_t)kvh * SEQ + kcol0) * HD, HD, s_m, tid);
  __syncthreads();

  f32x4 P[2][8], R[2][8];
  const f32x4 z4 = {0.f, 0.f, 0.f, 0.f};
#pragma unroll
  for (int rg = 0; rg < 2; ++rg)
#pragma unroll
    for (int cg = 0; cg < 8; ++cg) { P[rg][cg] = z4; R[rg][cg] = z4; }

#pragma unroll
  for (int ks = 0; ks < 4; ++ks) {
    const int d0 = ks * 32 + fg * 8;
    const int c16 = ks * 4 + fg;
    const bf16x8 a0 = *(const bf16x8*)&qg[(size_t)(qrow0 + fr) * HD + d0];
    const bf16x8 a1 = *(const bf16x8*)&qg[(size_t)(qrow0 + 16 + fr) * HD + d0];
#pragma unroll
    for (int cg = 0; cg < 8; ++cg) {
      const bf16x8 bz = frag_b(s_z, cg * 16 + fr, c16);
      const bf16x8 bm = frag_b(s_m, cg * 16 + fr, c16);
      P[0][cg] = __builtin_amdgcn_mfma_f32_16x16x32_bf16(a0, bz, P[0][cg], 0, 0, 0);
      P[1][cg] = __builtin_amdgcn_mfma_f32_16x16x32_bf16(a1, bz, P[1][cg], 0, 0, 0);
      R[0][cg] = __builtin_amdgcn_mfma_f32_16x16x32_bf16(a0, bm, R[0][cg], 0, 0, 0);
      R[1][cg] = __builtin_amdgcn_mfma_f32_16x16x32_bf16(a1, bm, R[1][cg], 0, 0, 0);
    }
  }
#pragma unroll
  for (int cg = 0; cg < 8; ++cg) {
    const int col = kcol0 + cg * 16 + fr;
    const float Z = Zk[kvh * SEQ + col], M = Mk[kvh * SEQ + col];
    const float base = qlo * (klo * Z + ksc * M);
#pragma unroll
    for (int rg = 0; rg < 2; ++rg)
#pragma unroll
      for (int r = 0; r < 4; ++r) {
        const int row = qrow0 + rg * 16 + fg * 4 + r;
        qdot[((size_t)h * SEQ + row) * SEQ + col] =
            base + qsc * (klo * P[rg][cg][r] + ksc * R[rg][cg][r]);
      }
  }
}

// ---------------- softmax: causal skip + stoch-quant + softmax ----------------
__global__ __launch_bounds__(256) void softmax_kernel(
    float* __restrict__ attn, const float* __restrict__ cw,
    unsigned* __restrict__ slots, uint32_t uk0, uint32_t uk1) {
  const int row = blockIdx.x;          // h*SEQ + qi
  const int qi = row & (SEQ - 1);
  const int tid = threadIdx.x;
  const float lo = cw[24], hi = cw[25], sc = cw[26], sci = cw[28];
  float* prow = attn + (size_t)row * SEQ;
  const uint32_t jbase = (uint32_t)row << 11;

  float vals[8];
  float lmax = -INFINITY;
#pragma unroll
  for (int m = 0; m < 2; ++m) {
    int ki = m * 1024 + tid * 4;
    if (ki <= qi) {
      float4 x4 = *(const float4*)&prow[ki];
      float xa[4] = {x4.x, x4.y, x4.z, x4.w};
#pragma unroll
      for (int j = 0; j < 4; ++j) {
        if (ki + j <= qi) {
          float u = tf_uniform(uk0, uk1, jbase + (uint32_t)(ki + j));
          float lg = fq_st_i(xa[j], lo, hi, sc, sci, u) * SCALING_F;
          vals[m * 4 + j] = lg;
          lmax = fmaxf(lmax, lg);
        } else {
          vals[m * 4 + j] = -INFINITY;
        }
      }
    } else {
      vals[m * 4 + 0] = vals[m * 4 + 1] = vals[m * 4 + 2] = vals[m * 4 + 3] = -INFINITY;
    }
  }

  __shared__ float smax[4], ssum[4], smn[4], smx[4];
#pragma unroll
  for (int off = 32; off > 0; off >>= 1) lmax = fmaxf(lmax, __shfl_xor(lmax, off));
  if ((tid & 63) == 0) smax[tid >> 6] = lmax;
  __syncthreads();
  float rmax = fmaxf(fmaxf(smax[0], smax[1]), fmaxf(smax[2], smax[3]));

  float lsum = 0.f;
#pragma unroll
  for (int e = 0; e < 8; ++e) { vals[e] = __expf(vals[e] - rmax); lsum += vals[e]; }
#pragma unroll
  for (int off = 32; off > 0; off >>= 1) lsum += __shfl_xor(lsum, off);
  if ((tid & 63) == 0) ssum[tid >> 6] = lsum;
  __syncthreads();
  float rinv = 1.0f / (ssum[0] + ssum[1] + ssum[2] + ssum[3]);

  float lmin2 = INFINITY, lmax2 = -INFINITY;
#pragma unroll
  for (int m = 0; m < 2; ++m) {
    int ki = m * 1024 + tid * 4;
    float4 st;
    float* stp = (float*)&st;
#pragma unroll
    for (int j = 0; j < 4; ++j) {
      float w = vals[m * 4 + j] * rinv;
      stp[j] = w;
      lmin2 = fminf(lmin2, w);
      lmax2 = fmaxf(lmax2, w);
    }
    *(float4*)&prow[ki] = st;
  }
#pragma unroll
  for (int off = 32; off > 0; off >>= 1) {
    lmin2 = fminf(lmin2, __shfl_xor(lmin2, off));
    lmax2 = fmaxf(lmax2, __shfl_xor(lmax2, off));
  }
  if ((tid & 63) == 0) { smn[tid >> 6] = lmin2; smx[tid >> 6] = lmax2; }
  __syncthreads();
  if (tid == 0) {
    float mn = fminf(fminf(smn[0], smn[1]), fminf(smn[2], smn[3]));
    float mx = fmaxf(fmaxf(smx[0], smx[1]), fmaxf(smx[2], smx[3]));
    push_minmax(slots, fmono(mn), fmono(mx));
  }
}

// ---------------- packers ----------------
__device__ __forceinline__ void pack_split8(const float* __restrict__ p,
                                            f16x8* ah, f16x8* al) {
  float4 w0 = *(const float4*)p;
  float4 w1 = *(const float4*)(p + 4);
  float wa[8] = {w0.x, w0.y, w0.z, w0.w, w1.x, w1.y, w1.z, w1.w};
  f16x8 h, l;
#pragma unroll
  for (int j = 0; j < 8; ++j) {
    _Float16 hf = (_Float16)wa[j];
    h[j] = hf;
    l[j] = (_Float16)(wa[j] - (float)hf);
  }
  *ah = h; *al = l;
}

__device__ __forceinline__ bf16x8 pack_a8(const float* __restrict__ ar,
                                          float lo, float hi, float sc) {
  float4 w0 = *(const float4*)ar;
  float4 w1 = *(const float4*)(ar + 4);
  float wa[8] = {w0.x, w0.y, w0.z, w0.w, w1.x, w1.y, w1.z, w1.w};
  bf16x8 r;
#pragma unroll
  for (int j = 0; j < 8; ++j) {
    float n = rintf((fminf(fmaxf(wa[j], lo), hi) - lo) / sc);
    r[j] = (short)(__float_as_uint(n) >> 16);
  }
  return r;
}

// ---------------- AV raw (3-term f16 MFMA), LDS-staged V ----------------
__global__ __launch_bounds__(256, 2) void av_raw_mfma(
    const float* __restrict__ attn, const unsigned short* __restrict__ vhT,
    const unsigned short* __restrict__ vlT, unsigned* __restrict__ slots) {
  __shared__ __align__(16) unsigned short s_h[128 * 128];
  __shared__ __align__(16) unsigned short s_l[128 * 128];
  const int qbi = (int)gridDim.x - 1 - (int)blockIdx.x;  // largest blocks first
  const int h = blockIdx.y, kvh = h >> 2;
  const int tid = threadIdx.x;
  const int wid = tid >> 6, lane = tid & 63;
  const int fr = lane & 15, fg = lane >> 4;
  const int qrow0 = qbi * 128 + wid * 32;
  const float* ag = attn + (size_t)h * SEQ * SEQ;
  const unsigned short* bhg = vhT + (size_t)kvh * HD * SEQ;
  const unsigned short* blg = vlT + (size_t)kvh * HD * SEQ;
  const int nc = qbi + 1;   // 128-kp chunks; beyond qb+127 attn is exactly 0
  f32x4 acc[2][8];
  const f32x4 z4 = {0.f, 0.f, 0.f, 0.f};
#pragma unroll
  for (int rg = 0; rg < 2; ++rg)
#pragma unroll
    for (int cg = 0; cg < 8; ++cg) acc[rg][cg] = z4;

  for (int c = 0; c < nc; ++c) {
    __syncthreads();
    stage_panel(bhg + c * 128, SEQ, s_h, tid);
    stage_panel(blg + c * 128, SEQ, s_l, tid);
    __syncthreads();
#pragma unroll
    for (int ks = 0; ks < 4; ++ks) {
      const int kp0 = c * 128 + ks * 32 + fg * 8;
      const int c16 = ks * 4 + fg;
      f16x8 a0h, a0l, a1h, a1l;
      pack_split8(ag + (size_t)(qrow0 + fr) * SEQ + kp0, &a0h, &a0l);
      pack_split8(ag + (size_t)(qrow0 + 16 + fr) * SEQ + kp0, &a1h, &a1l);
#pragma unroll
      for (int cg = 0; cg < 8; ++cg) {
        const f16x8 bh = frag_h(s_h, cg * 16 + fr, c16);
        const f16x8 bl = frag_h(s_l, cg * 16 + fr, c16);
        acc[0][cg] = __builtin_amdgcn_mfma_f32_16x16x32_f16(a0h, bh, acc[0][cg], 0, 0, 0);
        acc[0][cg] = __builtin_amdgcn_mfma_f32_16x16x32_f16(a0h, bl, acc[0][cg], 0, 0, 0);
        acc[0][cg] = __builtin_amdgcn_mfma_f32_16x16x32_f16(a0l, bh, acc[0][cg], 0, 0, 0);
        acc[1][cg] = __builtin_amdgcn_mfma_f32_16x16x32_f16(a1h, bh, acc[1][cg], 0, 0, 0);
        acc[1][cg] = __builtin_amdgcn_mfma_f32_16x16x32_f16(a1h, bl, acc[1][cg], 0, 0, 0);
        acc[1][cg] = __builtin_amdgcn_mfma_f32_16x16x32_f16(a1l, bh, acc[1][cg], 0, 0, 0);
      }
    }
  }
  float lmin = INFINITY, lmax = -INFINITY;
#pragma unroll
  for (int rg = 0; rg < 2; ++rg)
#pragma unroll
    for (int cg = 0; cg < 8; ++cg)
#pragma unroll
      for (int r = 0; r < 4; ++r) {
        lmin = fminf(lmin, acc[rg][cg][r]);
        lmax = fmaxf(lmax, acc[rg][cg][r]);
      }
  __shared__ unsigned bmin, bmax;
  if (tid == 0) { bmin = 0xFFFFFFFFu; bmax = 0u; }
  __syncthreads();
  atomicMin(&bmin, fmono(lmin));
  atomicMax(&bmax, fmono(lmax));
  __syncthreads();
  if (tid == 0) push_minmax(slots, bmin, bmax);
}

// ---------------- AV quant + fused final stochastic quantization ----------------
__global__ __launch_bounds__(256, 2) void av_quant_kernel(
    const float* __restrict__ attn, const unsigned short* __restrict__ vzT,
    const unsigned short* __restrict__ vmT, float* __restrict__ out0,
    const float* __restrict__ cw, uint32_t uk0, uint32_t uk1) {
  __shared__ __align__(16) unsigned short s_z[128 * 128];
  __shared__ __align__(16) unsigned short s_m[128 * 128];
  const int qbi = (int)gridDim.x - 1 - (int)blockIdx.x;
  const int h = blockIdx.y, kvh = h >> 2;
  const float alo = cw[32], ahi = cw[33], asc = cw[34];
  const float vlo = cw[16], vsc = cw[18];
  const float slo = cw[40], shi = cw[41], ssc = cw[42], ssci = cw[44];
  const int tid = threadIdx.x;
  const int wid = tid >> 6, lane = tid & 63;
  const int fr = lane & 15, fg = lane >> 4;
  const int qrow0 = qbi * 128 + wid * 32;
  const float* ag = attn + (size_t)h * SEQ * SEQ;
  const unsigned short* zg = vzT + (size_t)kvh * HD * SEQ;
  const unsigned short* mg = vmT + (size_t)kvh * HD * SEQ;
  const int nc = qbi + 1;
  f32x4 P[2][8], R[2][8];
  const f32x4 z4 = {0.f, 0.f, 0.f, 0.f};
#pragma unroll
  for (int rg = 0; rg < 2; ++rg)
#pragma unroll
    for (int cg = 0; cg < 8; ++cg) { P[rg][cg] = z4; R[rg][cg] = z4; }

  for (int c = 0; c < nc; ++c) {
    __syncthreads();
    stage_panel(zg + c * 128, SEQ, s_z, tid);
    stage_panel(mg + c * 128, SEQ, s_m, tid);
    __syncthreads();
#pragma unroll
    for (int ks = 0; ks < 4; ++ks) {
      const int kp0 = c * 128 + ks * 32 + fg * 8;
      const int c16 = ks * 4 + fg;
      const bf16x8 a0 = pack_a8(ag + (size_t)(qrow0 + fr) * SEQ + kp0, alo, ahi, asc);
      const bf16x8 a1 = pack_a8(ag + (size_t)(qrow0 + 16 + fr) * SEQ + kp0, alo, ahi, asc);
#pragma unroll
      for (int cg = 0; cg < 8; ++cg) {
        const bf16x8 bz = frag_b(s_z, cg * 16 + fr, c16);
        const bf16x8 bm = frag_b(s_m, cg * 16 + fr, c16);
        P[0][cg] = __builtin_amdgcn_mfma_f32_16x16x32_bf16(a0, bz, P[0][cg], 0, 0, 0);
        P[1][cg] = __builtin_amdgcn_mfma_f32_16x16x32_bf16(a1, bz, P[1][cg], 0, 0, 0);
        R[0][cg] = __builtin_amdgcn_mfma_f32_16x16x32_bf16(a0, bm, R[0][cg], 0, 0, 0);
        R[1][cg] = __builtin_amdgcn_mfma_f32_16x16x32_bf16(a1, bm, R[1][cg], 0, 0, 0);
      }
    }
  }
#pragma unroll
  for (int cg = 0; cg < 8; ++cg) {
    const int dcol = cg * 16 + fr;
#pragma unroll
    for (int rg = 0; rg < 2; ++rg)
#pragma unroll
      for (int r = 0; r < 4; ++r) {
        const int row = qrow0 + rg * 16 + fg * 4 + r;
        const float val = asc * (vlo * P[rg][cg][r] + vsc * R[rg][cg][r]);
        const uint32_t j = ((uint32_t)h * SEQ + (uint32_t)row) * HD + (uint32_t)dcol;
        const float u = tf_uniform(uk0, uk1, j);
        out0[((size_t)row * NH + h) * HD + dcol] = fq_st_i(val, slo, shi, ssc, ssci, u);
      }
  }
}

// ---------------- launcher ----------------
extern "C" void kernel_launch(void* const* d_in, const int* in_sizes, int n_in,
                              void* d_out, int out_size, void* d_ws, size_t ws_size,
                              hipStream_t stream) {
  (void)in_sizes; (void)n_in; (void)out_size; (void)ws_size;
  const float* q      = (const float*)d_in[0];
  const float* k      = (const float*)d_in[1];
  const float* v      = (const float*)d_in[2];
  const float* q_old  = (const float*)d_in[4];
  const float* k_old  = (const float*)d_in[5];
  const float* qk_old = (const float*)d_in[6];
  const float* a_old  = (const float*)d_in[7];
  const float* v_old  = (const float*)d_in[8];
  const float* av_old = (const float*)d_in[9];
  float* out0 = (float*)d_out;
  float* out1 = out0 + (size_t)OUT0_N;
  unsigned* su = (unsigned*)d_ws;
  float* cw = (float*)d_ws + 16;

  // d_ws scratch: vzT/vmT (live until av_quant), Zk/Mk  (~8.5 MB)
  unsigned short* vzT = (unsigned short*)((char*)d_ws + 1024);
  unsigned short* vmT = vzT + (size_t)NKVH * SEQ * HD;
  float* Zk = (float*)(vmT + (size_t)NKVH * SEQ * HD);
  float* Mk = Zk + NKVH * SEQ;

  // out0-region scratch (exactly fills 32 MB; all consumed before av_quant
  // overwrites out0): qnb(16MB) kzb(4MB) kmb(4MB) vhT(4MB) vlT(4MB)
  unsigned short* qnb = (unsigned short*)out0;
  unsigned short* kzb = qnb + (size_t)NH * SEQ * HD;
  unsigned short* kmb = kzb + (size_t)NKVH * SEQ * HD;
  unsigned short* vhT = kmb + (size_t)NKVH * SEQ * HD;
  unsigned short* vlT = vhT + (size_t)NKVH * SEQ * HD;

  // out1-region scratch (consumed by qk_raw_mfma before qk_quant writes out1)
  unsigned short* qh = (unsigned short*)out1;
  unsigned short* ql = qh + (size_t)NH * SEQ * HD;
  unsigned short* kh = ql + (size_t)NH * SEQ * HD;
  unsigned short* kl = kh + (size_t)NKVH * SEQ * HD;

  uint32_t kq0, kq1, ka0, ka1;
  tf2x32(0u, 0u, 0u, 0u, &kq0, &kq1);
  tf2x32(0u, 0u, 0u, 1u, &ka0, &ka1);

  init_ws<<<1, 32, 0, stream>>>(su);
  minmax3_kernel<<<2048, 256, 0, stream>>>((const float4*)q, (const float4*)k,
                                           (const float4*)v, su);
  finalize3_kernel<<<1, 32, 0, stream>>>(su, q_old, k_old, v_old, cw);
  prep_kernel<<<PREP_QB + PREP_KB + PREP_VB, 256, 0, stream>>>(
      q, k, v, qnb, qh, ql, kzb, kmb, kh, kl, Zk, Mk, vzT, vmT, vhT, vlT, cw);

  qk_raw_mfma<<<dim3(16, 8, NH), 256, 0, stream>>>(qh, ql, kh, kl, su + 6);
  finalize_kernel<<<1, 1, 0, stream>>>(su + 6, qk_old, cw + 24);
  qk_quant_kernel<<<dim3(16, 16, NH), 256, 0, stream>>>(qnb, kzb, kmb, Zk, Mk, out1, cw);

  softmax_kernel<<<NH * SEQ, 256, 0, stream>>>(out1, cw, su + 8, kq0, kq1);
  finalize_kernel<<<1, 1, 0, stream>>>(su + 8, a_old, cw + 32);

  av_raw_mfma<<<dim3(16, NH), 256, 0, stream>>>(out1, vhT, vlT, su + 10);
  finalize_kernel<<<1, 1, 0, stream>>>(su + 10, av_old, cw + 40);
  av_quant_kernel<<<dim3(16, NH), 256, 0, stream>>>(out1, vzT, vmT, out0, cw, ka0, ka1);
}